// Round 4
// baseline (563.326 us; speedup 1.0000x reference)
//
#include <hip/hip_runtime.h>
#include <cstdint>
#include <cstddef>

#define NN 50000
#define NE 200000
#define IND 768
#define HID 256
#define OUTD 64
#define NB 196  // ceil(NN/256)

typedef __bf16 bf16;
typedef __bf16 bf16x8 __attribute__((ext_vector_type(8)));
typedef __bf16 bf16x4 __attribute__((ext_vector_type(4)));
typedef float f32x4 __attribute__((ext_vector_type(4)));

// ---------------- init: le=-1, deg=0 (replaces 2 memsets) ----------------
__global__ __launch_bounds__(256) void k_init(int* __restrict__ le, int* __restrict__ deg) {
  int i = blockIdx.x * 256 + threadIdx.x;
  if (i < NN) { le[i] = -1; deg[i] = 0; }
}

// ---------------- edge prep: last-write-wins scatter index + dst histogram ----------------
__global__ __launch_bounds__(256) void k_edge_prep(const int* __restrict__ ei,
                                                   int* __restrict__ le, int* __restrict__ deg) {
  int e = blockIdx.x * 256 + threadIdx.x;
  if (e < NE) {
    atomicMax(&le[ei[e]], e);        // src: last edge index wins
    atomicAdd(&deg[ei[NE + e]], 1);  // dst degree
  }
}

// ---------------- weights: W1t, W2t transposes + eW = eemb @ W1 (row 6 = 0) ----------------
// grid dim3(4, 256): bx<3 -> W1t; bx==3, by<64 -> W2t; by in [64,71) -> eW
__global__ __launch_bounds__(256) void k_weights(const float* __restrict__ W1,
                                                 const float* __restrict__ W2,
                                                 const float* __restrict__ eemb,
                                                 bf16* __restrict__ W1t,
                                                 bf16* __restrict__ W2t,
                                                 float* __restrict__ eW) {
  int bx = blockIdx.x, by = blockIdx.y, tid = threadIdx.x;
  if (bx < 3) {
    int k = bx * 256 + tid;
    W1t[by * IND + k] = (bf16)W1[(size_t)k * HID + by];
  } else if (by < OUTD) {
    W2t[by * HID + tid] = (bf16)W2[(size_t)tid * OUTD + by];
  } else if (by < OUTD + 7) {
    int r = by - OUTD;
    float s = 0.f;
    if (r < 6) {
      for (int k = 0; k < IND; ++k) s += eemb[r * IND + k] * W1[(size_t)k * HID + tid];
    }
    eW[r * HID + tid] = s;  // row 6 = zeros ("no edge")
  }
}

// ---------------- CSR build: scan + scatter ----------------
__global__ __launch_bounds__(256) void k_scan_block(const int* __restrict__ deg,
                                                    int* __restrict__ excl, int* __restrict__ bsum) {
  __shared__ int sm[256];
  int tid = threadIdx.x;
  int i = blockIdx.x * 256 + tid;
  int v = (i < NN) ? deg[i] : 0;
  sm[tid] = v;
  __syncthreads();
#pragma unroll
  for (int off = 1; off < 256; off <<= 1) {
    int t = (tid >= off) ? sm[tid - off] : 0;
    __syncthreads();
    sm[tid] += t;
    __syncthreads();
  }
  if (i < NN) excl[i] = sm[tid] - v;
  if (tid == 255) bsum[blockIdx.x] = sm[255];
}

__global__ __launch_bounds__(256) void k_scan_partials(const int* __restrict__ bsum,
                                                       int* __restrict__ bbase) {
  __shared__ int sm[256];
  int tid = threadIdx.x;
  int v = (tid < NB) ? bsum[tid] : 0;
  sm[tid] = v;
  __syncthreads();
#pragma unroll
  for (int off = 1; off < 256; off <<= 1) {
    int t = (tid >= off) ? sm[tid - off] : 0;
    __syncthreads();
    sm[tid] += t;
    __syncthreads();
  }
  bbase[tid] = sm[tid] - v;
}

// also derives eidx[i] = edge-type row for node i (6 = none) for the GEMM1 epilogue
__global__ __launch_bounds__(256) void k_add_base(const int* __restrict__ excl,
                                                  const int* __restrict__ bbase,
                                                  int* __restrict__ rowstart, int* __restrict__ cur,
                                                  const int* __restrict__ le,
                                                  const int* __restrict__ et,
                                                  int* __restrict__ eidx) {
  int i = blockIdx.x * 256 + threadIdx.x;
  if (i < NN) {
    int rs = excl[i] + bbase[i >> 8];
    rowstart[i] = rs;
    cur[i] = rs;
    int l = le[i];
    eidx[i] = (l >= 0) ? et[l] : 6;
  }
}

__global__ __launch_bounds__(256) void k_scatter_csr(const int* __restrict__ ei,
                                                     int* __restrict__ cur, int* __restrict__ csr) {
  int e = blockIdx.x * 256 + threadIdx.x;
  if (e < NE) {
    int d = ei[NE + e];
    int pos = atomicAdd(&cur[d], 1);
    csr[pos] = ei[e];  // store src node id
  }
}

__device__ __forceinline__ void gld16(const bf16* g, bf16* l) {
  __builtin_amdgcn_global_load_lds((const __attribute__((address_space(1))) void*)g,
                                   (__attribute__((address_space(3))) void*)l, 16, 0, 0);
}

// ---------------- MFMA GEMM: C[M,NC] = A[M,K] * Bt[NC,K]^T ----------------
// 128xTN tile, BK=32, 4 waves. TN=128: 2x2 waves (4x4 frags); TN=64: 4x1 (2x4).
// FX=true (layer 1): A is fp32 x, reg-staged with in-flight bf16 convert.
//   2 register sets, issue->commit distance ~2.5 iters (covers HBM ~900cy);
//   B via global_load_lds (L2-resident W1t). One barrier/K-step, vmcnt(4)
//   steady state. Epilogue adds eW[eidx[row]] (linearity: (x+e)W = xW + eW).
// FX=false (layer 2): all-global_load_lds, TRIPLE buffer, distance-2,
//   vmcnt(3) steady state, one barrier/K-step.
// Epilogue also emits attention logits alS/alD (per-row dot with aS/aD).
template <typename OutT, int TN, bool FX>
__global__ __launch_bounds__(256) void k_gemm_bt(const bf16* __restrict__ A,
                                                 const float* __restrict__ Ax,
                                                 const bf16* __restrict__ Bt,
                                                 OutT* __restrict__ C,
                                                 int M, int K, int NC,
                                                 const float* __restrict__ aS,
                                                 const float* __restrict__ aD,
                                                 float* __restrict__ alS,
                                                 float* __restrict__ alD,
                                                 int alStride,
                                                 const int* __restrict__ eidx,
                                                 const float* __restrict__ eW) {
  constexpr int MI = (TN == 128) ? 4 : 2;
  constexpr int WROWS = MI * 16;
  constexpr int NBUF = FX ? 2 : 3;
  __shared__ bf16 As[NBUF][128 * 32];
  __shared__ bf16 Bs[NBUF][TN * 32];
  const int tid = threadIdx.x;
  const int lane = tid & 63;
  const int wave = tid >> 6;
  const int wr = (TN == 128) ? (wave >> 1) : wave;
  const int wc = (TN == 128) ? (wave & 1) : 0;
  const int ln15 = lane & 15, q = lane >> 4;
  const int n0 = blockIdx.x * TN;
  const int m0 = blockIdx.y * 128;

  // gld16 staging geometry: 64 lanes x 16B = 16 rows of [32] bf16 per call.
  const int sr = lane >> 2;
  const int scol = (lane & 3) * 8;
  const int gA0 = min(m0 + wave * 32 + sr, M - 1);
  const int gA1 = min(m0 + wave * 32 + 16 + sr, M - 1);
  int gB0, gB1 = 0;
  if constexpr (TN == 128) {
    gB0 = min(n0 + wave * 32 + sr, NC - 1);
    gB1 = min(n0 + wave * 32 + 16 + sr, NC - 1);
  } else {
    gB0 = min(n0 + wave * 16 + sr, NC - 1);
  }

  auto stageB = [&](int buf, int kt) {
    if constexpr (TN == 128) {
      gld16(Bt + (size_t)gB0 * K + kt + scol, &Bs[buf][(wave * 32) * 32]);
      gld16(Bt + (size_t)gB1 * K + kt + scol, &Bs[buf][(wave * 32 + 16) * 32]);
    } else {
      gld16(Bt + (size_t)gB0 * K + kt + scol, &Bs[buf][(wave * 16) * 32]);
    }
  };

  f32x4 acc[MI][4] = {};

  auto compute = [&](int buf) {
    bf16x8 af[MI], bfr[4];
#pragma unroll
    for (int i = 0; i < MI; i++)
      af[i] = *(const bf16x8*)(&As[buf][(wr * WROWS + i * 16 + ln15) * 32 + q * 8]);
#pragma unroll
    for (int i = 0; i < 4; i++)
      bfr[i] = *(const bf16x8*)(&Bs[buf][(wc * 64 + i * 16 + ln15) * 32 + q * 8]);
#pragma unroll
    for (int mi = 0; mi < MI; mi++)
#pragma unroll
      for (int ni = 0; ni < 4; ni++)
        acc[mi][ni] = __builtin_amdgcn_mfma_f32_16x16x32_bf16(af[mi], bfr[ni], acc[mi][ni], 0, 0, 0);
  };

  const int NT = K >> 5;

  if constexpr (FX) {
    // fp32 A reg-staged: thread covers rows r0, r0+64, cols ce..ce+7 (8 floats each)
    const int r0 = tid >> 2;
    const int ce = (tid & 3) << 3;
    const int rr0 = min(m0 + r0, M - 1);
    const int rr1 = min(m0 + 64 + r0, M - 1);
    const float* pA0 = Ax + (size_t)rr0 * K + ce;
    const float* pA1 = Ax + (size_t)rr1 * K + ce;
    struct ARegs { float4 a00, a01, a10, a11; };
    ARegs s0, s1;
    auto issueA = [&](ARegs& R, int kt) {
      R.a00 = *(const float4*)(pA0 + kt);
      R.a01 = *(const float4*)(pA0 + kt + 4);
      R.a10 = *(const float4*)(pA1 + kt);
      R.a11 = *(const float4*)(pA1 + kt + 4);
    };
    auto commitA = [&](int buf, const ARegs& R) {
      bf16x8 v0, v1;
      v0[0] = (bf16)R.a00.x; v0[1] = (bf16)R.a00.y; v0[2] = (bf16)R.a00.z; v0[3] = (bf16)R.a00.w;
      v0[4] = (bf16)R.a01.x; v0[5] = (bf16)R.a01.y; v0[6] = (bf16)R.a01.z; v0[7] = (bf16)R.a01.w;
      v1[0] = (bf16)R.a10.x; v1[1] = (bf16)R.a10.y; v1[2] = (bf16)R.a10.z; v1[3] = (bf16)R.a10.w;
      v1[4] = (bf16)R.a11.x; v1[5] = (bf16)R.a11.y; v1[6] = (bf16)R.a11.z; v1[7] = (bf16)R.a11.w;
      *(bf16x8*)(&As[buf][r0 * 32 + ce]) = v0;
      *(bf16x8*)(&As[buf][(64 + r0) * 32 + ce]) = v1;
    };

    // prologue: tiles 0,1,2 A-issued; tile 0 committed; B(0) staged  (NT >= 4)
    issueA(s0, 0);
    stageB(0, 0);
    issueA(s1, 32);
    commitA(0, s0);      // auto-waits A(0) only (vmcnt keeps B(0), A(1) in flight)
    issueA(s0, 64);
    int cur = 0;
    for (int t = 0; t < NT; ++t) {
      if (t == 0)          asm volatile("s_waitcnt vmcnt(8)" ::: "memory");
      else if (t < NT - 1) asm volatile("s_waitcnt vmcnt(4)" ::: "memory");
      else                 asm volatile("s_waitcnt vmcnt(0)" ::: "memory");
      __builtin_amdgcn_s_barrier();  // publish buf[cur]; free buf[cur^1]
      int nxt = cur ^ 1;
      if (t + 1 < NT) {
        stageB(nxt, (t + 1) << 5);
        commitA(nxt, ((t + 1) & 1) ? s1 : s0);  // regs issued ~2.5 iters ago
      }
      if (t + 3 < NT) issueA(((t + 3) & 1) ? s1 : s0, (t + 3) << 5);
      compute(cur);
      cur = nxt;
    }
  } else {
    // all-gld16 triple buffer, distance-2
    auto stageA = [&](int buf, int kt) {
      gld16(A + (size_t)gA0 * K + kt + scol, &As[buf][(wave * 32) * 32]);
      gld16(A + (size_t)gA1 * K + kt + scol, &As[buf][(wave * 32 + 16) * 32]);
    };
    stageA(0, 0); stageB(0, 0);
    stageA(1, 32); stageB(1, 32);
    for (int t = 0; t < NT; ++t) {
      if (t < NT - 1) asm volatile("s_waitcnt vmcnt(3)" ::: "memory");
      else            asm volatile("s_waitcnt vmcnt(0)" ::: "memory");
      __builtin_amdgcn_s_barrier();  // publish tile t; free buf of tile t-1
      if (t + 2 < NT) {
        int b = (t + 2) % 3;
        stageA(b, (t + 2) << 5); stageB(b, (t + 2) << 5);
      }
      compute(t % 3);
    }
  }

  // epilogue 0 (FX): acc += eW[eidx[row]][col]   (fold of the x+e edge-emb)
  if constexpr (FX) {
#pragma unroll
    for (int mi = 0; mi < MI; mi++)
#pragma unroll
      for (int r = 0; r < 4; r++) {
        int row = m0 + wr * WROWS + mi * 16 + q * 4 + r;
        int e = eidx[min(row, M - 1)];
        const float* ew = eW + e * HID + n0 + wc * 64 + ln15;
#pragma unroll
        for (int ni = 0; ni < 4; ni++) acc[mi][ni][r] += ew[ni * 16];
      }
  }

  // epilogue 1: C store. C/D layout col=lane&15, row=(lane>>4)*4+reg
#pragma unroll
  for (int mi = 0; mi < MI; mi++)
#pragma unroll
    for (int ni = 0; ni < 4; ni++)
#pragma unroll
      for (int r = 0; r < 4; r++) {
        int row = m0 + wr * WROWS + mi * 16 + q * 4 + r;
        int col = n0 + wc * 64 + ni * 16 + ln15;
        if (row < M && col < NC) C[(size_t)row * NC + col] = (OutT)acc[mi][ni][r];
      }

  // epilogue 2: attention logits. Each wave's 64-col slice == one head slice;
  // each (row, hd) produced by exactly one wave grid-wide -> plain stores.
  if (n0 + wc * 64 < NC) {
    const int hd = (n0 + wc * 64) >> 6;
#pragma unroll
    for (int mi = 0; mi < MI; mi++)
#pragma unroll
      for (int r = 0; r < 4; r++) {
        float ps = 0.f, pd = 0.f;
#pragma unroll
        for (int ni = 0; ni < 4; ni++) {
          int col = n0 + wc * 64 + ni * 16 + ln15;
          float w_s = (col < NC) ? aS[col] : 0.f;
          float w_d = (col < NC) ? aD[col] : 0.f;
          ps += acc[mi][ni][r] * w_s;
          pd += acc[mi][ni][r] * w_d;
        }
#pragma unroll
        for (int off = 1; off < 16; off <<= 1) {
          ps += __shfl_xor(ps, off);
          pd += __shfl_xor(pd, off);
        }
        int row = m0 + wr * WROWS + mi * 16 + q * 4 + r;
        if (ln15 == 0 && row < M) {
          alS[row * alStride + hd] = ps;
          alD[row * alStride + hd] = pd;
        }
      }
  }
}

// ---------------- fused gather-aggregate + LN + ELU, layer 1 ----------------
// 1 wave = 1 node (64 lanes x 4 feats, bf16x4 = 8B/lane gather loads);
// LN reduction is a pure wave shuffle — no LDS, no __syncthreads.
__global__ __launch_bounds__(256) void k_agg_ln1(const int* __restrict__ rowstart,
                                                 const int* __restrict__ deg,
                                                 const int* __restrict__ csr,
                                                 const bf16* __restrict__ h1,
                                                 const float* __restrict__ alS,
                                                 const float* __restrict__ alD,
                                                 const float* __restrict__ b1,
                                                 const float* __restrict__ g1,
                                                 const float* __restrict__ be1,
                                                 bf16* __restrict__ hln) {
  const int n = blockIdx.x * 4 + (threadIdx.x >> 6);  // 50000 % 4 == 0
  const int lane = threadIdx.x & 63;
  const int f0 = lane * 4;       // 4 consecutive feats, same head (4 | 64)
  const int hd = lane >> 4;
  int start = rowstart[n], cnt = deg[n];
  float ald = alD[n * 4 + hd];
  float accv0 = 0.f, accv1 = 0.f, accv2 = 0.f, accv3 = 0.f, accw = 0.f;
  for (int j = 0; j < cnt; j++) {
    int s = csr[start + j];
    float logit = alS[s * 4 + hd] + ald;
    logit = logit >= 0.f ? logit : 0.2f * logit;
    float w = __expf(logit);  // shift-free softmax: logits bounded by construction
    bf16x4 hv = *(const bf16x4*)(h1 + (size_t)s * HID + f0);
    accv0 += w * (float)hv[0];
    accv1 += w * (float)hv[1];
    accv2 += w * (float)hv[2];
    accv3 += w * (float)hv[3];
    accw += w;
  }
  float inv = (cnt > 0) ? 1.f / accw : 0.f;
  float4 bv = *(const float4*)(b1 + f0);
  float v0 = accv0 * inv + bv.x;
  float v1 = accv1 * inv + bv.y;
  float v2 = accv2 * inv + bv.z;
  float v3 = accv3 * inv + bv.w;
  float s = v0 + v1 + v2 + v3;
  float ss = v0 * v0 + v1 * v1 + v2 * v2 + v3 * v3;
#pragma unroll
  for (int off = 32; off; off >>= 1) { s += __shfl_xor(s, off); ss += __shfl_xor(ss, off); }
  float mu = s * (1.f / HID);
  float var = ss * (1.f / HID) - mu * mu;
  float rs = rsqrtf(var + 1e-5f);
  float4 gv = *(const float4*)(g1 + f0);
  float4 ev = *(const float4*)(be1 + f0);
  float y0 = (v0 - mu) * rs * gv.x + ev.x;
  float y1 = (v1 - mu) * rs * gv.y + ev.y;
  float y2 = (v2 - mu) * rs * gv.z + ev.z;
  float y3 = (v3 - mu) * rs * gv.w + ev.w;
  y0 = y0 > 0.f ? y0 : __expf(y0) - 1.f;  // ELU
  y1 = y1 > 0.f ? y1 : __expf(y1) - 1.f;
  y2 = y2 > 0.f ? y2 : __expf(y2) - 1.f;
  y3 = y3 > 0.f ? y3 : __expf(y3) - 1.f;
  bf16x4 o;
  o[0] = (bf16)y0; o[1] = (bf16)y1; o[2] = (bf16)y2; o[3] = (bf16)y3;
  *(bf16x4*)(hln + (size_t)n * HID + f0) = o;
}

// ---------------- fused gather-aggregate + LN, layer 2 ----------------
// 1 wave = 1 node (64 lanes x 1 fp32 feat); wave-shuffle LN.
__global__ __launch_bounds__(256) void k_agg_ln2(const int* __restrict__ rowstart,
                                                 const int* __restrict__ deg,
                                                 const int* __restrict__ csr,
                                                 const float* __restrict__ h2,
                                                 const float* __restrict__ alS,
                                                 const float* __restrict__ alD,
                                                 const float* __restrict__ b2,
                                                 const float* __restrict__ g2,
                                                 const float* __restrict__ be2,
                                                 float* __restrict__ out) {
  const int n = blockIdx.x * 4 + (threadIdx.x >> 6);
  const int f = threadIdx.x & 63;
  int start = rowstart[n], cnt = deg[n];
  float ald = alD[n];
  float accv = 0.f, accw = 0.f;
  for (int j = 0; j < cnt; j++) {
    int s = csr[start + j];
    float logit = alS[s] + ald;
    logit = logit >= 0.f ? logit : 0.2f * logit;
    float w = __expf(logit);
    accv += w * h2[(size_t)s * OUTD + f];
    accw += w;
  }
  float v = (cnt > 0) ? accv / accw : 0.f;
  v += b2[f];
  float s = v, ss = v * v;
#pragma unroll
  for (int off = 32; off; off >>= 1) { s += __shfl_xor(s, off); ss += __shfl_xor(ss, off); }
  float mu = s * (1.f / OUTD);
  float var = ss * (1.f / OUTD) - mu * mu;
  out[(size_t)n * OUTD + f] = (v - mu) * rsqrtf(var + 1e-5f) * g2[f] + be2[f];
}

extern "C" void kernel_launch(void* const* d_in, const int* in_sizes, int n_in,
                              void* d_out, int out_size, void* d_ws, size_t ws_size,
                              hipStream_t stream) {
  const float* x    = (const float*)d_in[0];
  const int*   ei   = (const int*)d_in[1];
  const int*   et   = (const int*)d_in[2];
  const float* eemb = (const float*)d_in[3];
  const float* W1   = (const float*)d_in[4];
  const float* as1  = (const float*)d_in[5];
  const float* ad1  = (const float*)d_in[6];
  const float* b1   = (const float*)d_in[7];
  const float* g1   = (const float*)d_in[8];
  const float* be1  = (const float*)d_in[9];
  const float* W2   = (const float*)d_in[10];
  const float* as2  = (const float*)d_in[11];
  const float* ad2  = (const float*)d_in[12];
  const float* b2   = (const float*)d_in[13];
  const float* g2   = (const float*)d_in[14];
  const float* be2  = (const float*)d_in[15];
  float* out = (float*)d_out;

  char* base = (char*)d_ws;
  size_t off = 0;
  auto alloc = [&](size_t bytes) -> void* {
    void* p = base + off;
    off = (off + bytes + 255) & ~(size_t)255;
    return p;
  };
  int*   le    = (int*)alloc((size_t)NN * 4);
  int*   deg   = (int*)alloc((size_t)NN * 4);
  int*   excl  = (int*)alloc((size_t)NN * 4);
  int*   bsum  = (int*)alloc(256 * 4);
  int*   bbase = (int*)alloc(256 * 4);
  int*   rowst = (int*)alloc((size_t)NN * 4);
  int*   cur   = (int*)alloc((size_t)NN * 4);
  int*   eidx  = (int*)alloc((size_t)NN * 4);
  int*   csr   = (int*)alloc((size_t)NE * 4);
  bf16*  h1    = (bf16*)alloc((size_t)NN * HID * 2);
  float* alS1  = (float*)alloc((size_t)NN * 4 * 4);
  float* alD1  = (float*)alloc((size_t)NN * 4 * 4);
  bf16*  W1t   = (bf16*)alloc((size_t)HID * IND * 2);
  bf16*  W2t   = (bf16*)alloc((size_t)OUTD * HID * 2);
  float* eW    = (float*)alloc((size_t)7 * HID * 4);
  bf16*  hln   = (bf16*)alloc((size_t)NN * HID * 2);
  float* h2    = (float*)alloc((size_t)NN * OUTD * 4);
  float* alS2  = (float*)alloc((size_t)NN * 4);
  float* alD2  = (float*)alloc((size_t)NN * 4);

  // 11 launches total (was 14): init replaces 2 memsets; weights merges
  // eembz + 2 transposes (+ eW); prep_a eliminated via the eW epilogue fold.
  k_init<<<NB, 256, 0, stream>>>(le, deg);
  k_edge_prep<<<(NE + 255) / 256, 256, 0, stream>>>(ei, le, deg);
  k_weights<<<dim3(4, 256), 256, 0, stream>>>(W1, W2, eemb, W1t, W2t, eW);
  k_scan_block<<<NB, 256, 0, stream>>>(deg, excl, bsum);
  k_scan_partials<<<1, 256, 0, stream>>>(bsum, bbase);
  k_add_base<<<NB, 256, 0, stream>>>(excl, bbase, rowst, cur, le, et, eidx);
  k_scatter_csr<<<(NE + 255) / 256, 256, 0, stream>>>(ei, cur, csr);

  // layer 1: GEMM reads fp32 x directly (reg-staged A), epilogue adds eW
  k_gemm_bt<bf16, 128, true><<<dim3(2, (NN + 127) / 128), 256, 0, stream>>>(
      nullptr, x, W1t, h1, NN, IND, HID, as1, ad1, alS1, alD1, 4, eidx, eW);
  k_agg_ln1<<<NN / 4, 256, 0, stream>>>(rowst, deg, csr, h1, alS1, alD1, b1, g1, be1, hln);

  // layer 2: narrow GEMM (TN=64), triple-buffered gld16 pipeline
  k_gemm_bt<float, 64, false><<<dim3(1, (NN + 127) / 128), 256, 0, stream>>>(
      hln, nullptr, W2t, h2, NN, HID, OUTD, as2, ad2, alS2, alD2, 1, nullptr, nullptr);
  k_agg_ln2<<<NN / 4, 256, 0, stream>>>(rowst, deg, csr, h2, alS2, alD2, b2, g2, be2, out);
}

// Round 5
// 451.186 us; speedup vs baseline: 1.2485x; 1.2485x over previous
//
#include <hip/hip_runtime.h>
#include <cstdint>
#include <cstddef>

#define NN 50000
#define NE 200000
#define IND 768
#define HID 256
#define OUTD 64
#define NB 196  // ceil(NN/256)

typedef __bf16 bf16;
typedef __bf16 bf16x8 __attribute__((ext_vector_type(8)));
typedef __bf16 bf16x4 __attribute__((ext_vector_type(4)));
typedef float f32x4 __attribute__((ext_vector_type(4)));

// ---------------- init: le=-1, deg=0 (replaces 2 memsets) ----------------
__global__ __launch_bounds__(256) void k_init(int* __restrict__ le, int* __restrict__ deg) {
  int i = blockIdx.x * 256 + threadIdx.x;
  if (i < NN) { le[i] = -1; deg[i] = 0; }
}

// ---------------- edge prep: last-write-wins scatter index + dst histogram ----------------
__global__ __launch_bounds__(256) void k_edge_prep(const int* __restrict__ ei,
                                                   int* __restrict__ le, int* __restrict__ deg) {
  int e = blockIdx.x * 256 + threadIdx.x;
  if (e < NE) {
    atomicMax(&le[ei[e]], e);        // src: last edge index wins
    atomicAdd(&deg[ei[NE + e]], 1);  // dst degree
  }
}

// ---------------- weights: W1t, W2t transposes + eW = eemb @ W1 (row 6 = 0) ----------------
// grid dim3(4, 256): bx<3 -> W1t; bx==3, by<64 -> W2t; by in [64,71) -> eW
__global__ __launch_bounds__(256) void k_weights(const float* __restrict__ W1,
                                                 const float* __restrict__ W2,
                                                 const float* __restrict__ eemb,
                                                 bf16* __restrict__ W1t,
                                                 bf16* __restrict__ W2t,
                                                 float* __restrict__ eW) {
  int bx = blockIdx.x, by = blockIdx.y, tid = threadIdx.x;
  if (bx < 3) {
    int k = bx * 256 + tid;
    W1t[by * IND + k] = (bf16)W1[(size_t)k * HID + by];
  } else if (by < OUTD) {
    W2t[by * HID + tid] = (bf16)W2[(size_t)tid * OUTD + by];
  } else if (by < OUTD + 7) {
    int r = by - OUTD;
    float s = 0.f;
    if (r < 6) {
      for (int k = 0; k < IND; ++k) s += eemb[r * IND + k] * W1[(size_t)k * HID + tid];
    }
    eW[r * HID + tid] = s;  // row 6 = zeros ("no edge")
  }
}

// ---------------- CSR build: scan + scatter ----------------
__global__ __launch_bounds__(256) void k_scan_block(const int* __restrict__ deg,
                                                    int* __restrict__ excl, int* __restrict__ bsum) {
  __shared__ int sm[256];
  int tid = threadIdx.x;
  int i = blockIdx.x * 256 + tid;
  int v = (i < NN) ? deg[i] : 0;
  sm[tid] = v;
  __syncthreads();
#pragma unroll
  for (int off = 1; off < 256; off <<= 1) {
    int t = (tid >= off) ? sm[tid - off] : 0;
    __syncthreads();
    sm[tid] += t;
    __syncthreads();
  }
  if (i < NN) excl[i] = sm[tid] - v;
  if (tid == 255) bsum[blockIdx.x] = sm[255];
}

__global__ __launch_bounds__(256) void k_scan_partials(const int* __restrict__ bsum,
                                                       int* __restrict__ bbase) {
  __shared__ int sm[256];
  int tid = threadIdx.x;
  int v = (tid < NB) ? bsum[tid] : 0;
  sm[tid] = v;
  __syncthreads();
#pragma unroll
  for (int off = 1; off < 256; off <<= 1) {
    int t = (tid >= off) ? sm[tid - off] : 0;
    __syncthreads();
    sm[tid] += t;
    __syncthreads();
  }
  bbase[tid] = sm[tid] - v;
}

// also derives eidx[i] = edge-type row for node i (6 = none) for the GEMM1 epilogue
__global__ __launch_bounds__(256) void k_add_base(const int* __restrict__ excl,
                                                  const int* __restrict__ bbase,
                                                  int* __restrict__ rowstart, int* __restrict__ cur,
                                                  const int* __restrict__ le,
                                                  const int* __restrict__ et,
                                                  int* __restrict__ eidx) {
  int i = blockIdx.x * 256 + threadIdx.x;
  if (i < NN) {
    int rs = excl[i] + bbase[i >> 8];
    rowstart[i] = rs;
    cur[i] = rs;
    int l = le[i];
    eidx[i] = (l >= 0) ? et[l] : 6;
  }
}

__global__ __launch_bounds__(256) void k_scatter_csr(const int* __restrict__ ei,
                                                     int* __restrict__ cur, int* __restrict__ csr) {
  int e = blockIdx.x * 256 + threadIdx.x;
  if (e < NE) {
    int d = ei[NE + e];
    int pos = atomicAdd(&cur[d], 1);
    csr[pos] = ei[e];  // store src node id
  }
}

__device__ __forceinline__ void gld16(const bf16* g, bf16* l) {
  __builtin_amdgcn_global_load_lds((const __attribute__((address_space(1))) void*)g,
                                   (__attribute__((address_space(3))) void*)l, 16, 0, 0);
}

// ---------------- MFMA GEMM: C[M,NC] = A[M,K] * Bt[NC,K]^T ----------------
// 128xTN tile, BK=32, 4 waves. TN=128: 2x2 waves (4x4 frags); TN=64: 4x1 (2x4).
// FX=true (layer 1): A is fp32 x, reg-staged with in-flight bf16 convert.
//   K-loop statically unrolled by 2 so the two register sets are only ever
//   named by compile-time identity (NO runtime selection -> no scratch; the
//   round-4 regression was rule-#20 scratch from `cond ? s1 : s0`).
//   Issue->commit distance = 2 tiles; B via gld16 double-buffer; counted
//   vmcnt(10) steady state (newer than B(t): A(t+2)x4 + B(t+1)x2 + A(t+3)x4),
//   vmcnt(0) only on the final pair. Epilogue adds eW[eidx[row]]
//   (linearity: (x+e)W = xW + eW).
// FX=false (layer 2): all-gld16 TRIPLE buffer, distance-2, vmcnt(3) steady.
// Epilogue also emits attention logits alS/alD (per-row dot with aS/aD).
template <typename OutT, int TN, bool FX>
__global__ __launch_bounds__(256) void k_gemm_bt(const bf16* __restrict__ A,
                                                 const float* __restrict__ Ax,
                                                 const bf16* __restrict__ Bt,
                                                 OutT* __restrict__ C,
                                                 int M, int K, int NC,
                                                 const float* __restrict__ aS,
                                                 const float* __restrict__ aD,
                                                 float* __restrict__ alS,
                                                 float* __restrict__ alD,
                                                 int alStride,
                                                 const int* __restrict__ eidx,
                                                 const float* __restrict__ eW) {
  constexpr int MI = (TN == 128) ? 4 : 2;
  constexpr int WROWS = MI * 16;
  constexpr int NBUF = FX ? 2 : 3;
  __shared__ bf16 As[NBUF][128 * 32];
  __shared__ bf16 Bs[NBUF][TN * 32];
  const int tid = threadIdx.x;
  const int lane = tid & 63;
  const int wave = tid >> 6;
  const int wr = (TN == 128) ? (wave >> 1) : wave;
  const int wc = (TN == 128) ? (wave & 1) : 0;
  const int ln15 = lane & 15, q = lane >> 4;
  const int n0 = blockIdx.x * TN;
  const int m0 = blockIdx.y * 128;

  // gld16 staging geometry: 64 lanes x 16B = 16 rows of [32] bf16 per call.
  const int sr = lane >> 2;
  const int scol = (lane & 3) * 8;
  const int gA0 = min(m0 + wave * 32 + sr, M - 1);
  const int gA1 = min(m0 + wave * 32 + 16 + sr, M - 1);
  int gB0, gB1 = 0;
  if constexpr (TN == 128) {
    gB0 = min(n0 + wave * 32 + sr, NC - 1);
    gB1 = min(n0 + wave * 32 + 16 + sr, NC - 1);
  } else {
    gB0 = min(n0 + wave * 16 + sr, NC - 1);
  }

  auto stageB = [&](int buf, int kt) {
    if constexpr (TN == 128) {
      gld16(Bt + (size_t)gB0 * K + kt + scol, &Bs[buf][(wave * 32) * 32]);
      gld16(Bt + (size_t)gB1 * K + kt + scol, &Bs[buf][(wave * 32 + 16) * 32]);
    } else {
      gld16(Bt + (size_t)gB0 * K + kt + scol, &Bs[buf][(wave * 16) * 32]);
    }
  };

  f32x4 acc[MI][4] = {};

  auto compute = [&](int buf) {
    bf16x8 af[MI], bfr[4];
#pragma unroll
    for (int i = 0; i < MI; i++)
      af[i] = *(const bf16x8*)(&As[buf][(wr * WROWS + i * 16 + ln15) * 32 + q * 8]);
#pragma unroll
    for (int i = 0; i < 4; i++)
      bfr[i] = *(const bf16x8*)(&Bs[buf][(wc * 64 + i * 16 + ln15) * 32 + q * 8]);
#pragma unroll
    for (int mi = 0; mi < MI; mi++)
#pragma unroll
      for (int ni = 0; ni < 4; ni++)
        acc[mi][ni] = __builtin_amdgcn_mfma_f32_16x16x32_bf16(af[mi], bfr[ni], acc[mi][ni], 0, 0, 0);
  };

  const int NT = K >> 5;  // NT even (24 or 8)

  if constexpr (FX) {
    // fp32 A reg-staged: thread covers rows r0, r0+64, cols ce..ce+7
    const int r0 = tid >> 2;
    const int ce = (tid & 3) << 3;
    const int rr0 = min(m0 + r0, M - 1);
    const int rr1 = min(m0 + 64 + r0, M - 1);
    const float* pA0 = Ax + (size_t)rr0 * K + ce;
    const float* pA1 = Ax + (size_t)rr1 * K + ce;
    // two statically-named register sets (never selected at runtime)
    float4 s0a, s0b, s0c, s0d, s1a, s1b, s1c, s1d;

#define ISSUE_S0(kt) { s0a = *(const float4*)(pA0 + (kt)); \
                       s0b = *(const float4*)(pA0 + (kt) + 4); \
                       s0c = *(const float4*)(pA1 + (kt)); \
                       s0d = *(const float4*)(pA1 + (kt) + 4); }
#define ISSUE_S1(kt) { s1a = *(const float4*)(pA0 + (kt)); \
                       s1b = *(const float4*)(pA0 + (kt) + 4); \
                       s1c = *(const float4*)(pA1 + (kt)); \
                       s1d = *(const float4*)(pA1 + (kt) + 4); }
#define COMMIT_A(buf, Ra, Rb, Rc, Rd) { \
    bf16x8 v0, v1; \
    v0[0] = (bf16)Ra.x; v0[1] = (bf16)Ra.y; v0[2] = (bf16)Ra.z; v0[3] = (bf16)Ra.w; \
    v0[4] = (bf16)Rb.x; v0[5] = (bf16)Rb.y; v0[6] = (bf16)Rb.z; v0[7] = (bf16)Rb.w; \
    v1[0] = (bf16)Rc.x; v1[1] = (bf16)Rc.y; v1[2] = (bf16)Rc.z; v1[3] = (bf16)Rc.w; \
    v1[4] = (bf16)Rd.x; v1[5] = (bf16)Rd.y; v1[6] = (bf16)Rd.z; v1[7] = (bf16)Rd.w; \
    *(bf16x8*)(&As[buf][r0 * 32 + ce]) = v0; \
    *(bf16x8*)(&As[buf][(64 + r0) * 32 + ce]) = v1; }

    // prologue (NT >= 4): tiles 0,1 committed; tiles 2,3 in regs; B(0),B(1) staged
    ISSUE_S0(0);
    ISSUE_S1(32);
    stageB(0, 0);
    COMMIT_A(0, s0a, s0b, s0c, s0d);  // waits tile-0 loads (compiler vmcnt)
    ISSUE_S0(64);
    stageB(1, 32);
    COMMIT_A(1, s1a, s1b, s1c, s1d);  // waits tile-1 loads
    ISSUE_S1(96);
    asm volatile("s_waitcnt lgkmcnt(0)" ::: "memory");  // drain commit ds_writes

    for (int t = 0; t < NT; t += 2) {
      // ---- body0: tile t in buf0 (s0 holds A(t+2)) ----
      if (t + 2 < NT) asm volatile("s_waitcnt vmcnt(10)" ::: "memory");
      else            asm volatile("s_waitcnt vmcnt(0)" ::: "memory");
      __builtin_amdgcn_s_barrier();  // publish buf0 (B landed, A-writes drained prev phase)
      compute(0);
      asm volatile("s_waitcnt lgkmcnt(0)" ::: "memory");
      __builtin_amdgcn_s_barrier();  // WAR: all waves done reading buf0
      if (t + 2 < NT) {
        COMMIT_A(0, s0a, s0b, s0c, s0d);  // A(t+2) -> buf0
        stageB(0, (t + 2) << 5);          // B(t+2)
      }
      if (t + 4 < NT) ISSUE_S0((t + 4) << 5);
      // ---- body1: tile t+1 in buf1 (s1 holds A(t+3)) ----
      if (t + 4 < NT) asm volatile("s_waitcnt vmcnt(10)" ::: "memory");
      else            asm volatile("s_waitcnt vmcnt(0)" ::: "memory");
      __builtin_amdgcn_s_barrier();
      compute(1);
      if (t + 2 < NT) {
        asm volatile("s_waitcnt lgkmcnt(0)" ::: "memory");
        __builtin_amdgcn_s_barrier();
        if (t + 3 < NT) {
          COMMIT_A(1, s1a, s1b, s1c, s1d);  // A(t+3) -> buf1
          stageB(1, (t + 3) << 5);          // B(t+3)
        }
        if (t + 5 < NT) ISSUE_S1((t + 5) << 5);
      }
    }
#undef ISSUE_S0
#undef ISSUE_S1
#undef COMMIT_A
  } else {
    // all-gld16 triple buffer, distance-2
    auto stageA = [&](int buf, int kt) {
      gld16(A + (size_t)gA0 * K + kt + scol, &As[buf][(wave * 32) * 32]);
      gld16(A + (size_t)gA1 * K + kt + scol, &As[buf][(wave * 32 + 16) * 32]);
    };
    stageA(0, 0); stageB(0, 0);
    stageA(1, 32); stageB(1, 32);
    for (int t = 0; t < NT; ++t) {
      if (t < NT - 1) asm volatile("s_waitcnt vmcnt(3)" ::: "memory");
      else            asm volatile("s_waitcnt vmcnt(0)" ::: "memory");
      __builtin_amdgcn_s_barrier();  // publish tile t; free buf of tile t-1
      if (t + 2 < NT) {
        int b = (t + 2) % 3;
        stageA(b, (t + 2) << 5); stageB(b, (t + 2) << 5);
      }
      compute(t % 3);
    }
  }

  // epilogue 0 (FX): acc += eW[eidx[row]][col]   (fold of the x+e edge-emb)
  if constexpr (FX) {
#pragma unroll
    for (int mi = 0; mi < MI; mi++)
#pragma unroll
      for (int r = 0; r < 4; r++) {
        int row = m0 + wr * WROWS + mi * 16 + q * 4 + r;
        int e = eidx[min(row, M - 1)];
        const float* ew = eW + e * HID + n0 + wc * 64 + ln15;
#pragma unroll
        for (int ni = 0; ni < 4; ni++) acc[mi][ni][r] += ew[ni * 16];
      }
  }

  // epilogue 1: C store. C/D layout col=lane&15, row=(lane>>4)*4+reg
#pragma unroll
  for (int mi = 0; mi < MI; mi++)
#pragma unroll
    for (int ni = 0; ni < 4; ni++)
#pragma unroll
      for (int r = 0; r < 4; r++) {
        int row = m0 + wr * WROWS + mi * 16 + q * 4 + r;
        int col = n0 + wc * 64 + ni * 16 + ln15;
        if (row < M && col < NC) C[(size_t)row * NC + col] = (OutT)acc[mi][ni][r];
      }

  // epilogue 2: attention logits. Each wave's 64-col slice == one head slice;
  // each (row, hd) produced by exactly one wave grid-wide -> plain stores.
  if (n0 + wc * 64 < NC) {
    const int hd = (n0 + wc * 64) >> 6;
#pragma unroll
    for (int mi = 0; mi < MI; mi++)
#pragma unroll
      for (int r = 0; r < 4; r++) {
        float ps = 0.f, pd = 0.f;
#pragma unroll
        for (int ni = 0; ni < 4; ni++) {
          int col = n0 + wc * 64 + ni * 16 + ln15;
          float w_s = (col < NC) ? aS[col] : 0.f;
          float w_d = (col < NC) ? aD[col] : 0.f;
          ps += acc[mi][ni][r] * w_s;
          pd += acc[mi][ni][r] * w_d;
        }
#pragma unroll
        for (int off = 1; off < 16; off <<= 1) {
          ps += __shfl_xor(ps, off);
          pd += __shfl_xor(pd, off);
        }
        int row = m0 + wr * WROWS + mi * 16 + q * 4 + r;
        if (ln15 == 0 && row < M) {
          alS[row * alStride + hd] = ps;
          alD[row * alStride + hd] = pd;
        }
      }
  }
}

// ---------------- fused gather-aggregate + LN + ELU, layer 1 ----------------
// 1 wave = 1 node (64 lanes x 4 feats, bf16x4 = 8B/lane gather loads);
// LN reduction is a pure wave shuffle — no LDS, no __syncthreads.
__global__ __launch_bounds__(256) void k_agg_ln1(const int* __restrict__ rowstart,
                                                 const int* __restrict__ deg,
                                                 const int* __restrict__ csr,
                                                 const bf16* __restrict__ h1,
                                                 const float* __restrict__ alS,
                                                 const float* __restrict__ alD,
                                                 const float* __restrict__ b1,
                                                 const float* __restrict__ g1,
                                                 const float* __restrict__ be1,
                                                 bf16* __restrict__ hln) {
  const int n = blockIdx.x * 4 + (threadIdx.x >> 6);  // 50000 % 4 == 0
  const int lane = threadIdx.x & 63;
  const int f0 = lane * 4;       // 4 consecutive feats, same head (4 | 64)
  const int hd = lane >> 4;
  int start = rowstart[n], cnt = deg[n];
  float ald = alD[n * 4 + hd];
  float accv0 = 0.f, accv1 = 0.f, accv2 = 0.f, accv3 = 0.f, accw = 0.f;
  for (int j = 0; j < cnt; j++) {
    int s = csr[start + j];
    float logit = alS[s * 4 + hd] + ald;
    logit = logit >= 0.f ? logit : 0.2f * logit;
    float w = __expf(logit);  // shift-free softmax: logits bounded by construction
    bf16x4 hv = *(const bf16x4*)(h1 + (size_t)s * HID + f0);
    accv0 += w * (float)hv[0];
    accv1 += w * (float)hv[1];
    accv2 += w * (float)hv[2];
    accv3 += w * (float)hv[3];
    accw += w;
  }
  float inv = (cnt > 0) ? 1.f / accw : 0.f;
  float4 bv = *(const float4*)(b1 + f0);
  float v0 = accv0 * inv + bv.x;
  float v1 = accv1 * inv + bv.y;
  float v2 = accv2 * inv + bv.z;
  float v3 = accv3 * inv + bv.w;
  float s = v0 + v1 + v2 + v3;
  float ss = v0 * v0 + v1 * v1 + v2 * v2 + v3 * v3;
#pragma unroll
  for (int off = 32; off; off >>= 1) { s += __shfl_xor(s, off); ss += __shfl_xor(ss, off); }
  float mu = s * (1.f / HID);
  float var = ss * (1.f / HID) - mu * mu;
  float rs = rsqrtf(var + 1e-5f);
  float4 gv = *(const float4*)(g1 + f0);
  float4 ev = *(const float4*)(be1 + f0);
  float y0 = (v0 - mu) * rs * gv.x + ev.x;
  float y1 = (v1 - mu) * rs * gv.y + ev.y;
  float y2 = (v2 - mu) * rs * gv.z + ev.z;
  float y3 = (v3 - mu) * rs * gv.w + ev.w;
  y0 = y0 > 0.f ? y0 : __expf(y0) - 1.f;  // ELU
  y1 = y1 > 0.f ? y1 : __expf(y1) - 1.f;
  y2 = y2 > 0.f ? y2 : __expf(y2) - 1.f;
  y3 = y3 > 0.f ? y3 : __expf(y3) - 1.f;
  bf16x4 o;
  o[0] = (bf16)y0; o[1] = (bf16)y1; o[2] = (bf16)y2; o[3] = (bf16)y3;
  *(bf16x4*)(hln + (size_t)n * HID + f0) = o;
}

// ---------------- fused gather-aggregate + LN, layer 2 ----------------
// 1 wave = 1 node (64 lanes x 1 fp32 feat); wave-shuffle LN.
__global__ __launch_bounds__(256) void k_agg_ln2(const int* __restrict__ rowstart,
                                                 const int* __restrict__ deg,
                                                 const int* __restrict__ csr,
                                                 const float* __restrict__ h2,
                                                 const float* __restrict__ alS,
                                                 const float* __restrict__ alD,
                                                 const float* __restrict__ b2,
                                                 const float* __restrict__ g2,
                                                 const float* __restrict__ be2,
                                                 float* __restrict__ out) {
  const int n = blockIdx.x * 4 + (threadIdx.x >> 6);
  const int f = threadIdx.x & 63;
  int start = rowstart[n], cnt = deg[n];
  float ald = alD[n];
  float accv = 0.f, accw = 0.f;
  for (int j = 0; j < cnt; j++) {
    int s = csr[start + j];
    float logit = alS[s] + ald;
    logit = logit >= 0.f ? logit : 0.2f * logit;
    float w = __expf(logit);
    accv += w * h2[(size_t)s * OUTD + f];
    accw += w;
  }
  float v = (cnt > 0) ? accv / accw : 0.f;
  v += b2[f];
  float s = v, ss = v * v;
#pragma unroll
  for (int off = 32; off; off >>= 1) { s += __shfl_xor(s, off); ss += __shfl_xor(ss, off); }
  float mu = s * (1.f / OUTD);
  float var = ss * (1.f / OUTD) - mu * mu;
  out[(size_t)n * OUTD + f] = (v - mu) * rsqrtf(var + 1e-5f) * g2[f] + be2[f];
}

extern "C" void kernel_launch(void* const* d_in, const int* in_sizes, int n_in,
                              void* d_out, int out_size, void* d_ws, size_t ws_size,
                              hipStream_t stream) {
  const float* x    = (const float*)d_in[0];
  const int*   ei   = (const int*)d_in[1];
  const int*   et   = (const int*)d_in[2];
  const float* eemb = (const float*)d_in[3];
  const float* W1   = (const float*)d_in[4];
  const float* as1  = (const float*)d_in[5];
  const float* ad1  = (const float*)d_in[6];
  const float* b1   = (const float*)d_in[7];
  const float* g1   = (const float*)d_in[8];
  const float* be1  = (const float*)d_in[9];
  const float* W2   = (const float*)d_in[10];
  const float* as2  = (const float*)d_in[11];
  const float* ad2  = (const float*)d_in[12];
  const float* b2   = (const float*)d_in[13];
  const float* g2   = (const float*)d_in[14];
  const float* be2  = (const float*)d_in[15];
  float* out = (float*)d_out;

  char* base = (char*)d_ws;
  size_t off = 0;
  auto alloc = [&](size_t bytes) -> void* {
    void* p = base + off;
    off = (off + bytes + 255) & ~(size_t)255;
    return p;
  };
  int*   le    = (int*)alloc((size_t)NN * 4);
  int*   deg   = (int*)alloc((size_t)NN * 4);
  int*   excl  = (int*)alloc((size_t)NN * 4);
  int*   bsum  = (int*)alloc(256 * 4);
  int*   bbase = (int*)alloc(256 * 4);
  int*   rowst = (int*)alloc((size_t)NN * 4);
  int*   cur   = (int*)alloc((size_t)NN * 4);
  int*   eidx  = (int*)alloc((size_t)NN * 4);
  int*   csr   = (int*)alloc((size_t)NE * 4);
  bf16*  h1    = (bf16*)alloc((size_t)NN * HID * 2);
  float* alS1  = (float*)alloc((size_t)NN * 4 * 4);
  float* alD1  = (float*)alloc((size_t)NN * 4 * 4);
  bf16*  W1t   = (bf16*)alloc((size_t)HID * IND * 2);
  bf16*  W2t   = (bf16*)alloc((size_t)OUTD * HID * 2);
  float* eW    = (float*)alloc((size_t)7 * HID * 4);
  bf16*  hln   = (bf16*)alloc((size_t)NN * HID * 2);
  float* h2    = (float*)alloc((size_t)NN * OUTD * 4);
  float* alS2  = (float*)alloc((size_t)NN * 4);
  float* alD2  = (float*)alloc((size_t)NN * 4);

  // 11 launches: init replaces 2 memsets; weights merges eembz + 2 transposes
  // (+ eW); prep_a eliminated via the eW epilogue fold.
  k_init<<<NB, 256, 0, stream>>>(le, deg);
  k_edge_prep<<<(NE + 255) / 256, 256, 0, stream>>>(ei, le, deg);
  k_weights<<<dim3(4, 256), 256, 0, stream>>>(W1, W2, eemb, W1t, W2t, eW);
  k_scan_block<<<NB, 256, 0, stream>>>(deg, excl, bsum);
  k_scan_partials<<<1, 256, 0, stream>>>(bsum, bbase);
  k_add_base<<<NB, 256, 0, stream>>>(excl, bbase, rowst, cur, le, et, eidx);
  k_scatter_csr<<<(NE + 255) / 256, 256, 0, stream>>>(ei, cur, csr);

  // layer 1: GEMM reads fp32 x directly (static-unroll reg-staged A), epilogue adds eW
  k_gemm_bt<bf16, 128, true><<<dim3(2, (NN + 127) / 128), 256, 0, stream>>>(
      nullptr, x, W1t, h1, NN, IND, HID, as1, ad1, alS1, alD1, 4, eidx, eW);
  k_agg_ln1<<<NN / 4, 256, 0, stream>>>(rowst, deg, csr, h1, alS1, alD1, b1, g1, be1, hln);

  // layer 2: narrow GEMM (TN=64), triple-buffered gld16 pipeline
  k_gemm_bt<float, 64, false><<<dim3(1, (NN + 127) / 128), 256, 0, stream>>>(
      hln, nullptr, W2t, h2, NN, HID, OUTD, as2, ad2, alS2, alD2, 1, nullptr, nullptr);
  k_agg_ln2<<<NN / 4, 256, 0, stream>>>(rowst, deg, csr, h2, alS2, alD2, b2, g2, be2, out);
}

// Round 6
// 450.263 us; speedup vs baseline: 1.2511x; 1.0020x over previous
//
#include <hip/hip_runtime.h>
#include <cstdint>
#include <cstddef>

#define NN 50000
#define NE 200000
#define IND 768
#define HID 256
#define OUTD 64
#define NB 196    // ceil(NN/256)
#define NEB 782   // ceil(NE/256) edge-prep blocks
#define NWB 1024  // weights blocks (4 x 256 linearized)
#define NCB 18750 // cast blocks: NN*IND/8/256

typedef __bf16 bf16;
typedef __bf16 bf16x8 __attribute__((ext_vector_type(8)));
typedef __bf16 bf16x4 __attribute__((ext_vector_type(4)));
typedef float f32x4 __attribute__((ext_vector_type(4)));

// ---------------- front: edge-prep + weights (+eW) + fp32->bf16 cast, ONE launch ----------
// blocks [0,NEB): last-edge/degree atomics; [NEB,NEB+NWB): W1t/W2t transpose + eW=eemb@W1;
// [NEB+NWB, ...): A1 = bf16(x) streaming cast (dominates; hides the rest).
__global__ __launch_bounds__(256) void k_front(const int* __restrict__ ei,
                                               int* __restrict__ le, int* __restrict__ deg,
                                               const float* __restrict__ x,
                                               bf16* __restrict__ A1,
                                               const float* __restrict__ W1,
                                               const float* __restrict__ W2,
                                               const float* __restrict__ eemb,
                                               bf16* __restrict__ W1t,
                                               bf16* __restrict__ W2t,
                                               float* __restrict__ eW) {
  const int bid = blockIdx.x, tid = threadIdx.x;
  if (bid < NEB) {
    int e = bid * 256 + tid;
    if (e < NE) {
      atomicMax(&le[ei[e]], e);        // src: last edge index wins
      atomicAdd(&deg[ei[NE + e]], 1);  // dst degree
    }
  } else if (bid < NEB + NWB) {
    int wb = bid - NEB, bx = wb >> 8, by = wb & 255;
    if (bx < 3) {
      int k = bx * 256 + tid;
      W1t[by * IND + k] = (bf16)W1[(size_t)k * HID + by];
    } else if (by < OUTD) {
      W2t[by * HID + tid] = (bf16)W2[(size_t)tid * OUTD + by];
    } else if (by < OUTD + 7) {
      int r = by - OUTD;
      float s = 0.f;
      if (r < 6) {
        for (int k = 0; k < IND; ++k) s += eemb[r * IND + k] * W1[(size_t)k * HID + tid];
      }
      eW[r * HID + tid] = s;  // row 6 = zeros ("no edge")
    }
  } else {
    size_t idx = (size_t)(bid - NEB - NWB) * 256 + tid;  // one thread = 8 elems
    const float* px = x + idx * 8;
    float4 v0 = *(const float4*)px, v1 = *(const float4*)(px + 4);
    bf16x8 o;
    o[0] = (bf16)v0.x; o[1] = (bf16)v0.y; o[2] = (bf16)v0.z; o[3] = (bf16)v0.w;
    o[4] = (bf16)v1.x; o[5] = (bf16)v1.y; o[6] = (bf16)v1.z; o[7] = (bf16)v1.w;
    *(bf16x8*)(A1 + idx * 8) = o;
  }
}

// ---------------- CSR build: scan + scatter ----------------
__global__ __launch_bounds__(256) void k_scan_block(const int* __restrict__ deg,
                                                    int* __restrict__ excl, int* __restrict__ bsum) {
  __shared__ int sm[256];
  int tid = threadIdx.x;
  int i = blockIdx.x * 256 + tid;
  int v = (i < NN) ? deg[i] : 0;
  sm[tid] = v;
  __syncthreads();
#pragma unroll
  for (int off = 1; off < 256; off <<= 1) {
    int t = (tid >= off) ? sm[tid - off] : 0;
    __syncthreads();
    sm[tid] += t;
    __syncthreads();
  }
  if (i < NN) excl[i] = sm[tid] - v;
  if (tid == 255) bsum[blockIdx.x] = sm[255];
}

__global__ __launch_bounds__(256) void k_scan_partials(const int* __restrict__ bsum,
                                                       int* __restrict__ bbase) {
  __shared__ int sm[256];
  int tid = threadIdx.x;
  int v = (tid < NB) ? bsum[tid] : 0;
  sm[tid] = v;
  __syncthreads();
#pragma unroll
  for (int off = 1; off < 256; off <<= 1) {
    int t = (tid >= off) ? sm[tid - off] : 0;
    __syncthreads();
    sm[tid] += t;
    __syncthreads();
  }
  bbase[tid] = sm[tid] - v;
}

// also derives eidx[i] = edge-type row for node i (6 = none) for the GEMM1 epilogue
__global__ __launch_bounds__(256) void k_add_base(const int* __restrict__ excl,
                                                  const int* __restrict__ bbase,
                                                  int* __restrict__ rowstart, int* __restrict__ cur,
                                                  const int* __restrict__ le,
                                                  const int* __restrict__ et,
                                                  int* __restrict__ eidx) {
  int i = blockIdx.x * 256 + threadIdx.x;
  if (i < NN) {
    int rs = excl[i] + bbase[i >> 8];
    rowstart[i] = rs;
    cur[i] = rs;
    int l = le[i];
    eidx[i] = (l >= 0) ? et[l] : 6;
  }
}

__global__ __launch_bounds__(256) void k_scatter_csr(const int* __restrict__ ei,
                                                     int* __restrict__ cur, int* __restrict__ csr) {
  int e = blockIdx.x * 256 + threadIdx.x;
  if (e < NE) {
    int d = ei[NE + e];
    int pos = atomicAdd(&cur[d], 1);
    csr[pos] = ei[e];  // store src node id
  }
}

__device__ __forceinline__ void gld16(const bf16* g, bf16* l) {
  __builtin_amdgcn_global_load_lds((const __attribute__((address_space(1))) void*)g,
                                   (__attribute__((address_space(3))) void*)l, 16, 0, 0);
}

// ---------------- MFMA GEMM: C[M,NC] = A[M,K] * Bt[NC,K]^T ----------------
// All-global_load_lds staging (bf16 A), 128xTN tile, BK=32, 4 waves.
// TN=128: 2x2 waves (4x4 frags); TN=64: 4x1 (2x4 frags).
// TRIPLE-buffer, distance-2, ONE barrier per K-step:
//   [vmcnt(counted)] [barrier: publish tile t] [stage t+2] [compute t]
//   [lgkmcnt(0)+sched_barrier: reads done before next barrier]
// Stage target (t+2)%3 was last read at t-1; the lgkmcnt(0) before each
// barrier guarantees those reads completed -> WAR-safe without a 2nd barrier.
// Steady vmcnt = one stage's calls (4 for TN=128, 3 for TN=64); 0 only at tail.
// EW=true: epilogue adds eW[eidx[row]] (linearity: (x+e)W = xW + eW).
// Epilogue also emits attention logits alS/alD (per-row dot with aS/aD).
template <typename OutT, int TN, bool EW>
__global__ __launch_bounds__(256) void k_gemm_bt(const bf16* __restrict__ A,
                                                 const bf16* __restrict__ Bt,
                                                 OutT* __restrict__ C,
                                                 int M, int K, int NC,
                                                 const float* __restrict__ aS,
                                                 const float* __restrict__ aD,
                                                 float* __restrict__ alS,
                                                 float* __restrict__ alD,
                                                 int alStride,
                                                 const int* __restrict__ eidx,
                                                 const float* __restrict__ eW) {
  constexpr int MI = (TN == 128) ? 4 : 2;
  constexpr int WROWS = MI * 16;
  __shared__ bf16 As[3][128 * 32];
  __shared__ bf16 Bs[3][TN * 32];
  const int tid = threadIdx.x;
  const int lane = tid & 63;
  const int wave = tid >> 6;
  const int wr = (TN == 128) ? (wave >> 1) : wave;
  const int wc = (TN == 128) ? (wave & 1) : 0;
  const int ln15 = lane & 15, q = lane >> 4;
  const int n0 = blockIdx.x * TN;  // n fastest-varying: adjacent blocks share A-tile
  const int m0 = blockIdx.y * 128;

  // gld16 staging geometry: 64 lanes x 16B = 1KB = 16 rows of [32] bf16 per call.
  // lane l -> row +(l>>2), 16B chunk (l&3); LDS dest is wave-uniform base (linear).
  const int sr = lane >> 2;
  const int scol = (lane & 3) * 8;
  const int gA0 = min(m0 + wave * 32 + sr, M - 1);
  const int gA1 = min(m0 + wave * 32 + 16 + sr, M - 1);
  int gB0, gB1 = 0;
  if constexpr (TN == 128) {
    gB0 = min(n0 + wave * 32 + sr, NC - 1);
    gB1 = min(n0 + wave * 32 + 16 + sr, NC - 1);
  } else {
    gB0 = min(n0 + wave * 16 + sr, NC - 1);
  }

  auto stage = [&](int buf, int kt) {
    gld16(A + (size_t)gA0 * K + kt + scol, &As[buf][(wave * 32) * 32]);
    gld16(A + (size_t)gA1 * K + kt + scol, &As[buf][(wave * 32 + 16) * 32]);
    if constexpr (TN == 128) {
      gld16(Bt + (size_t)gB0 * K + kt + scol, &Bs[buf][(wave * 32) * 32]);
      gld16(Bt + (size_t)gB1 * K + kt + scol, &Bs[buf][(wave * 32 + 16) * 32]);
    } else {
      gld16(Bt + (size_t)gB0 * K + kt + scol, &Bs[buf][(wave * 16) * 32]);
    }
  };

  f32x4 acc[MI][4] = {};

  auto compute = [&](int buf) {
    bf16x8 af[MI], bfr[4];
#pragma unroll
    for (int i = 0; i < MI; i++)
      af[i] = *(const bf16x8*)(&As[buf][(wr * WROWS + i * 16 + ln15) * 32 + q * 8]);
#pragma unroll
    for (int i = 0; i < 4; i++)
      bfr[i] = *(const bf16x8*)(&Bs[buf][(wc * 64 + i * 16 + ln15) * 32 + q * 8]);
#pragma unroll
    for (int mi = 0; mi < MI; mi++)
#pragma unroll
      for (int ni = 0; ni < 4; ni++)
        acc[mi][ni] = __builtin_amdgcn_mfma_f32_16x16x32_bf16(af[mi], bfr[ni], acc[mi][ni], 0, 0, 0);
  };

  const int NT = K >> 5;

  stage(0, 0);
  stage(1, 32);
  for (int t = 0; t < NT; ++t) {
    if (t + 2 < NT) {
      if constexpr (TN == 128) asm volatile("s_waitcnt vmcnt(4)" ::: "memory");
      else                     asm volatile("s_waitcnt vmcnt(3)" ::: "memory");
    } else {
      asm volatile("s_waitcnt vmcnt(0)" ::: "memory");
    }
    __builtin_amdgcn_sched_barrier(0);
    __builtin_amdgcn_s_barrier();  // publish tile t
    if (t + 2 < NT) stage((t + 2) % 3, (t + 2) << 5);  // issue early, lands in ~2 iters
    compute(t % 3);
    // all my ds_reads of tile t complete before I signal the next barrier
    asm volatile("s_waitcnt lgkmcnt(0)" ::: "memory");
    __builtin_amdgcn_sched_barrier(0);
  }

  // epilogue 0 (EW): acc += eW[eidx[row]][col]   (fold of the x+e edge-emb)
  if constexpr (EW) {
#pragma unroll
    for (int mi = 0; mi < MI; mi++)
#pragma unroll
      for (int r = 0; r < 4; r++) {
        int row = m0 + wr * WROWS + mi * 16 + q * 4 + r;
        int e = eidx[min(row, M - 1)];
        const float* ew = eW + e * HID + n0 + wc * 64 + ln15;
#pragma unroll
        for (int ni = 0; ni < 4; ni++) acc[mi][ni][r] += ew[ni * 16];
      }
  }

  // epilogue 1: C store. C/D layout col=lane&15, row=(lane>>4)*4+reg
#pragma unroll
  for (int mi = 0; mi < MI; mi++)
#pragma unroll
    for (int ni = 0; ni < 4; ni++)
#pragma unroll
      for (int r = 0; r < 4; r++) {
        int row = m0 + wr * WROWS + mi * 16 + q * 4 + r;
        int col = n0 + wc * 64 + ni * 16 + ln15;
        if (row < M && col < NC) C[(size_t)row * NC + col] = (OutT)acc[mi][ni][r];
      }

  // epilogue 2: attention logits. Each wave's 64-col slice == one head slice;
  // each (row, hd) produced by exactly one wave grid-wide -> plain stores.
  if (n0 + wc * 64 < NC) {
    const int hd = (n0 + wc * 64) >> 6;
#pragma unroll
    for (int mi = 0; mi < MI; mi++)
#pragma unroll
      for (int r = 0; r < 4; r++) {
        float ps = 0.f, pd = 0.f;
#pragma unroll
        for (int ni = 0; ni < 4; ni++) {
          int col = n0 + wc * 64 + ni * 16 + ln15;
          float w_s = (col < NC) ? aS[col] : 0.f;
          float w_d = (col < NC) ? aD[col] : 0.f;
          ps += acc[mi][ni][r] * w_s;
          pd += acc[mi][ni][r] * w_d;
        }
#pragma unroll
        for (int off = 1; off < 16; off <<= 1) {
          ps += __shfl_xor(ps, off);
          pd += __shfl_xor(pd, off);
        }
        int row = m0 + wr * WROWS + mi * 16 + q * 4 + r;
        if (ln15 == 0 && row < M) {
          alS[row * alStride + hd] = ps;
          alD[row * alStride + hd] = pd;
        }
      }
  }
}

// ---------------- fused gather-aggregate + LN + ELU, layer 1 ----------------
// 1 wave = 1 node (64 lanes x 4 feats, bf16x4 = 8B/lane gather loads);
// LN reduction is a pure wave shuffle — no LDS, no __syncthreads.
__global__ __launch_bounds__(256) void k_agg_ln1(const int* __restrict__ rowstart,
                                                 const int* __restrict__ deg,
                                                 const int* __restrict__ csr,
                                                 const bf16* __restrict__ h1,
                                                 const float* __restrict__ alS,
                                                 const float* __restrict__ alD,
                                                 const float* __restrict__ b1,
                                                 const float* __restrict__ g1,
                                                 const float* __restrict__ be1,
                                                 bf16* __restrict__ hln) {
  const int n = blockIdx.x * 4 + (threadIdx.x >> 6);  // 50000 % 4 == 0
  const int lane = threadIdx.x & 63;
  const int f0 = lane * 4;       // 4 consecutive feats, same head (4 | 64)
  const int hd = lane >> 4;
  int start = rowstart[n], cnt = deg[n];
  float ald = alD[n * 4 + hd];
  float accv0 = 0.f, accv1 = 0.f, accv2 = 0.f, accv3 = 0.f, accw = 0.f;
  for (int j = 0; j < cnt; j++) {
    int s = csr[start + j];
    float logit = alS[s * 4 + hd] + ald;
    logit = logit >= 0.f ? logit : 0.2f * logit;
    float w = __expf(logit);  // shift-free softmax: logits bounded by construction
    bf16x4 hv = *(const bf16x4*)(h1 + (size_t)s * HID + f0);
    accv0 += w * (float)hv[0];
    accv1 += w * (float)hv[1];
    accv2 += w * (float)hv[2];
    accv3 += w * (float)hv[3];
    accw += w;
  }
  float inv = (cnt > 0) ? 1.f / accw : 0.f;
  float4 bv = *(const float4*)(b1 + f0);
  float v0 = accv0 * inv + bv.x;
  float v1 = accv1 * inv + bv.y;
  float v2 = accv2 * inv + bv.z;
  float v3 = accv3 * inv + bv.w;
  float s = v0 + v1 + v2 + v3;
  float ss = v0 * v0 + v1 * v1 + v2 * v2 + v3 * v3;
#pragma unroll
  for (int off = 32; off; off >>= 1) { s += __shfl_xor(s, off); ss += __shfl_xor(ss, off); }
  float mu = s * (1.f / HID);
  float var = ss * (1.f / HID) - mu * mu;
  float rs = rsqrtf(var + 1e-5f);
  float4 gv = *(const float4*)(g1 + f0);
  float4 ev = *(const float4*)(be1 + f0);
  float y0 = (v0 - mu) * rs * gv.x + ev.x;
  float y1 = (v1 - mu) * rs * gv.y + ev.y;
  float y2 = (v2 - mu) * rs * gv.z + ev.z;
  float y3 = (v3 - mu) * rs * gv.w + ev.w;
  y0 = y0 > 0.f ? y0 : __expf(y0) - 1.f;  // ELU
  y1 = y1 > 0.f ? y1 : __expf(y1) - 1.f;
  y2 = y2 > 0.f ? y2 : __expf(y2) - 1.f;
  y3 = y3 > 0.f ? y3 : __expf(y3) - 1.f;
  bf16x4 o;
  o[0] = (bf16)y0; o[1] = (bf16)y1; o[2] = (bf16)y2; o[3] = (bf16)y3;
  *(bf16x4*)(hln + (size_t)n * HID + f0) = o;
}

// ---------------- fused gather-aggregate + LN, layer 2 ----------------
// 1 wave = 1 node (64 lanes x 1 fp32 feat); wave-shuffle LN.
__global__ __launch_bounds__(256) void k_agg_ln2(const int* __restrict__ rowstart,
                                                 const int* __restrict__ deg,
                                                 const int* __restrict__ csr,
                                                 const float* __restrict__ h2,
                                                 const float* __restrict__ alS,
                                                 const float* __restrict__ alD,
                                                 const float* __restrict__ b2,
                                                 const float* __restrict__ g2,
                                                 const float* __restrict__ be2,
                                                 float* __restrict__ out) {
  const int n = blockIdx.x * 4 + (threadIdx.x >> 6);
  const int f = threadIdx.x & 63;
  int start = rowstart[n], cnt = deg[n];
  float ald = alD[n];
  float accv = 0.f, accw = 0.f;
  for (int j = 0; j < cnt; j++) {
    int s = csr[start + j];
    float logit = alS[s] + ald;
    logit = logit >= 0.f ? logit : 0.2f * logit;
    float w = __expf(logit);
    accv += w * h2[(size_t)s * OUTD + f];
    accw += w;
  }
  float v = (cnt > 0) ? accv / accw : 0.f;
  v += b2[f];
  float s = v, ss = v * v;
#pragma unroll
  for (int off = 32; off; off >>= 1) { s += __shfl_xor(s, off); ss += __shfl_xor(ss, off); }
  float mu = s * (1.f / OUTD);
  float var = ss * (1.f / OUTD) - mu * mu;
  out[(size_t)n * OUTD + f] = (v - mu) * rsqrtf(var + 1e-5f) * g2[f] + be2[f];
}

extern "C" void kernel_launch(void* const* d_in, const int* in_sizes, int n_in,
                              void* d_out, int out_size, void* d_ws, size_t ws_size,
                              hipStream_t stream) {
  const float* x    = (const float*)d_in[0];
  const int*   ei   = (const int*)d_in[1];
  const int*   et   = (const int*)d_in[2];
  const float* eemb = (const float*)d_in[3];
  const float* W1   = (const float*)d_in[4];
  const float* as1  = (const float*)d_in[5];
  const float* ad1  = (const float*)d_in[6];
  const float* b1   = (const float*)d_in[7];
  const float* g1   = (const float*)d_in[8];
  const float* be1  = (const float*)d_in[9];
  const float* W2   = (const float*)d_in[10];
  const float* as2  = (const float*)d_in[11];
  const float* ad2  = (const float*)d_in[12];
  const float* b2   = (const float*)d_in[13];
  const float* g2   = (const float*)d_in[14];
  const float* be2  = (const float*)d_in[15];
  float* out = (float*)d_out;

  char* base = (char*)d_ws;
  size_t off = 0;
  auto alloc = [&](size_t bytes) -> void* {
    void* p = base + off;
    off = (off + bytes + 255) & ~(size_t)255;
    return p;
  };
  int*   le    = (int*)alloc((size_t)NN * 4);
  int*   deg   = (int*)alloc((size_t)NN * 4);
  int*   excl  = (int*)alloc((size_t)NN * 4);
  int*   bsum  = (int*)alloc(256 * 4);
  int*   bbase = (int*)alloc(256 * 4);
  int*   rowst = (int*)alloc((size_t)NN * 4);
  int*   cur   = (int*)alloc((size_t)NN * 4);
  int*   eidx  = (int*)alloc((size_t)NN * 4);
  int*   csr   = (int*)alloc((size_t)NE * 4);
  bf16*  h1    = (bf16*)alloc((size_t)NN * HID * 2);
  float* alS1  = (float*)alloc((size_t)NN * 4 * 4);
  float* alD1  = (float*)alloc((size_t)NN * 4 * 4);
  bf16*  W1t   = (bf16*)alloc((size_t)HID * IND * 2);
  bf16*  W2t   = (bf16*)alloc((size_t)OUTD * HID * 2);
  float* eW    = (float*)alloc((size_t)7 * HID * 4);
  // region R: A1 (live front..gemm1) aliased by {hln, h2, alS2, alD2} (live after gemm1)
  char*  R     = (char*)alloc((size_t)NN * IND * 2);
  bf16*  A1    = (bf16*)R;
  bf16*  hln   = (bf16*)R;
  float* h2    = (float*)(R + (size_t)NN * HID * 2);
  float* alS2  = (float*)(R + (size_t)NN * HID * 2 + (size_t)NN * OUTD * 4);
  float* alD2  = (float*)(R + (size_t)NN * HID * 2 + (size_t)NN * OUTD * 4 + (size_t)NN * 4);

  hipMemsetAsync(le, 0xFF, (size_t)NN * 4, stream);  // -1
  hipMemsetAsync(deg, 0, (size_t)NN * 4, stream);

  // one front launch: edge prep + weight transposes + eW + x->bf16 cast
  k_front<<<NEB + NWB + NCB, 256, 0, stream>>>(ei, le, deg, x, A1, W1, W2, eemb, W1t, W2t, eW);
  k_scan_block<<<NB, 256, 0, stream>>>(deg, excl, bsum);
  k_scan_partials<<<1, 256, 0, stream>>>(bsum, bbase);
  k_add_base<<<NB, 256, 0, stream>>>(excl, bbase, rowst, cur, le, et, eidx);
  k_scatter_csr<<<NEB, 256, 0, stream>>>(ei, cur, csr);

  // layer 1: all-gld16 pipelined bf16 GEMM, epilogue adds eW
  k_gemm_bt<bf16, 128, true><<<dim3(2, (NN + 127) / 128), 256, 0, stream>>>(
      A1, W1t, h1, NN, IND, HID, as1, ad1, alS1, alD1, 4, eidx, eW);
  k_agg_ln1<<<NN / 4, 256, 0, stream>>>(rowst, deg, csr, h1, alS1, alD1, b1, g1, be1, hln);

  // layer 2: narrow GEMM (TN=64), same pipeline
  k_gemm_bt<float, 64, false><<<dim3(1, (NN + 127) / 128), 256, 0, stream>>>(
      hln, W2t, h2, NN, HID, OUTD, as2, ad2, alS2, alD2, 1, nullptr, nullptr);
  k_agg_ln2<<<NN / 4, 256, 0, stream>>>(rowst, deg, csr, h2, alS2, alD2, b2, g2, be2, out);
}

// Round 7
// 447.222 us; speedup vs baseline: 1.2596x; 1.0068x over previous
//
#include <hip/hip_runtime.h>
#include <cstdint>
#include <cstddef>

#define NN 50000
#define NE 200000
#define IND 768
#define HID 256
#define OUTD 64
#define NB 196    // ceil(NN/256)
#define NEB 782   // ceil(NE/256) edge-prep blocks
#define NWB 1024  // weights blocks (4 x 256 linearized)
#define NCB 2048  // grid-stride cast blocks (G11: persistent waves, ~9 iters/thread)

typedef __bf16 bf16;
typedef __bf16 bf16x8 __attribute__((ext_vector_type(8)));
typedef __bf16 bf16x4 __attribute__((ext_vector_type(4)));
typedef float f32x4 __attribute__((ext_vector_type(4)));

// ---------------- front: cast (grid-stride) + edge-prep + weights, ONE launch ----------
// blocks [0,NCB): A1 = bf16(x) grid-stride streaming cast (long-running, launched FIRST);
// [NCB,NCB+NEB): last-edge/degree atomics; [NCB+NEB,NCB+NEB+NWB): W1t/W2t + eW=eemb@W1.
// Round-6 postmortem: one-shot cast (1 iter/thread, 20556 blocks) was CP-launch-rate
// bound at 21% HBM / 55% occupancy. Grid-stride keeps waves resident and pipelines
// loads across iterations (m13's 6.3 TB/s copy structure).
__global__ __launch_bounds__(256) void k_front(const int* __restrict__ ei,
                                               int* __restrict__ le, int* __restrict__ deg,
                                               const float* __restrict__ x,
                                               bf16* __restrict__ A1,
                                               const float* __restrict__ W1,
                                               const float* __restrict__ W2,
                                               const float* __restrict__ eemb,
                                               bf16* __restrict__ W1t,
                                               bf16* __restrict__ W2t,
                                               float* __restrict__ eW) {
  const int bid = blockIdx.x, tid = threadIdx.x;
  if (bid < NCB) {
    const size_t total = (size_t)NN * IND / 8;  // 8 elems per thread-iteration
    for (size_t idx = (size_t)bid * 256 + tid; idx < total; idx += (size_t)NCB * 256) {
      const float* px = x + idx * 8;
      float4 v0 = *(const float4*)px, v1 = *(const float4*)(px + 4);
      bf16x8 o;
      o[0] = (bf16)v0.x; o[1] = (bf16)v0.y; o[2] = (bf16)v0.z; o[3] = (bf16)v0.w;
      o[4] = (bf16)v1.x; o[5] = (bf16)v1.y; o[6] = (bf16)v1.z; o[7] = (bf16)v1.w;
      *(bf16x8*)(A1 + idx * 8) = o;
    }
  } else if (bid < NCB + NEB) {
    int e = (bid - NCB) * 256 + tid;
    if (e < NE) {
      atomicMax(&le[ei[e]], e);        // src: last edge index wins
      atomicAdd(&deg[ei[NE + e]], 1);  // dst degree
    }
  } else {
    int wb = bid - NCB - NEB, bx = wb >> 8, by = wb & 255;
    if (bx < 3) {
      int k = bx * 256 + tid;
      W1t[by * IND + k] = (bf16)W1[(size_t)k * HID + by];
    } else if (by < OUTD) {
      W2t[by * HID + tid] = (bf16)W2[(size_t)tid * OUTD + by];
    } else if (by < OUTD + 7) {
      int r = by - OUTD;
      float s = 0.f;
      if (r < 6) {
        for (int k = 0; k < IND; ++k) s += eemb[r * IND + k] * W1[(size_t)k * HID + tid];
      }
      eW[r * HID + tid] = s;  // row 6 = zeros ("no edge")
    }
  }
}

// ---------------- CSR build: scan + scatter ----------------
__global__ __launch_bounds__(256) void k_scan_block(const int* __restrict__ deg,
                                                    int* __restrict__ excl, int* __restrict__ bsum) {
  __shared__ int sm[256];
  int tid = threadIdx.x;
  int i = blockIdx.x * 256 + tid;
  int v = (i < NN) ? deg[i] : 0;
  sm[tid] = v;
  __syncthreads();
#pragma unroll
  for (int off = 1; off < 256; off <<= 1) {
    int t = (tid >= off) ? sm[tid - off] : 0;
    __syncthreads();
    sm[tid] += t;
    __syncthreads();
  }
  if (i < NN) excl[i] = sm[tid] - v;
  if (tid == 255) bsum[blockIdx.x] = sm[255];
}

__global__ __launch_bounds__(256) void k_scan_partials(const int* __restrict__ bsum,
                                                       int* __restrict__ bbase) {
  __shared__ int sm[256];
  int tid = threadIdx.x;
  int v = (tid < NB) ? bsum[tid] : 0;
  sm[tid] = v;
  __syncthreads();
#pragma unroll
  for (int off = 1; off < 256; off <<= 1) {
    int t = (tid >= off) ? sm[tid - off] : 0;
    __syncthreads();
    sm[tid] += t;
    __syncthreads();
  }
  bbase[tid] = sm[tid] - v;
}

// also derives eidx[i] = edge-type row for node i (6 = none) for the GEMM1 epilogue
__global__ __launch_bounds__(256) void k_add_base(const int* __restrict__ excl,
                                                  const int* __restrict__ bbase,
                                                  int* __restrict__ rowstart, int* __restrict__ cur,
                                                  const int* __restrict__ le,
                                                  const int* __restrict__ et,
                                                  int* __restrict__ eidx) {
  int i = blockIdx.x * 256 + threadIdx.x;
  if (i < NN) {
    int rs = excl[i] + bbase[i >> 8];
    rowstart[i] = rs;
    cur[i] = rs;
    int l = le[i];
    eidx[i] = (l >= 0) ? et[l] : 6;
  }
}

__global__ __launch_bounds__(256) void k_scatter_csr(const int* __restrict__ ei,
                                                     int* __restrict__ cur, int* __restrict__ csr) {
  int e = blockIdx.x * 256 + threadIdx.x;
  if (e < NE) {
    int d = ei[NE + e];
    int pos = atomicAdd(&cur[d], 1);
    csr[pos] = ei[e];  // store src node id
  }
}

__device__ __forceinline__ void gld16(const bf16* g, bf16* l) {
  __builtin_amdgcn_global_load_lds((const __attribute__((address_space(1))) void*)g,
                                   (__attribute__((address_space(3))) void*)l, 16, 0, 0);
}

// ---------------- MFMA GEMM: C[M,NC] = A[M,K] * Bt[NC,K]^T ----------------
// All-global_load_lds staging (bf16 A), 128xTN tile, BK=32, 4 waves.
// TN=128: 2x2 waves (4x4 frags); TN=64: 4x1 (2x4 frags).
// TRIPLE-buffer, distance-2, ONE barrier per K-step:
//   [vmcnt(counted)] [barrier: publish tile t] [stage t+2] [compute t]
//   [lgkmcnt(0)+sched_barrier: reads done before next barrier]
// Stage target (t+2)%3 was last read at t-1; the lgkmcnt(0) before each
// barrier guarantees those reads completed -> WAR-safe without a 2nd barrier.
// Steady vmcnt = one stage's calls (4 for TN=128, 3 for TN=64); 0 only at tail.
// EW=true: epilogue adds eW[eidx[row]] (linearity: (x+e)W = xW + eW).
// Epilogue also emits attention logits alS/alD (per-row dot with aS/aD).
template <typename OutT, int TN, bool EW>
__global__ __launch_bounds__(256) void k_gemm_bt(const bf16* __restrict__ A,
                                                 const bf16* __restrict__ Bt,
                                                 OutT* __restrict__ C,
                                                 int M, int K, int NC,
                                                 const float* __restrict__ aS,
                                                 const float* __restrict__ aD,
                                                 float* __restrict__ alS,
                                                 float* __restrict__ alD,
                                                 int alStride,
                                                 const int* __restrict__ eidx,
                                                 const float* __restrict__ eW) {
  constexpr int MI = (TN == 128) ? 4 : 2;
  constexpr int WROWS = MI * 16;
  __shared__ bf16 As[3][128 * 32];
  __shared__ bf16 Bs[3][TN * 32];
  const int tid = threadIdx.x;
  const int lane = tid & 63;
  const int wave = tid >> 6;
  const int wr = (TN == 128) ? (wave >> 1) : wave;
  const int wc = (TN == 128) ? (wave & 1) : 0;
  const int ln15 = lane & 15, q = lane >> 4;
  const int n0 = blockIdx.x * TN;  // n fastest-varying: adjacent blocks share A-tile
  const int m0 = blockIdx.y * 128;

  // gld16 staging geometry: 64 lanes x 16B = 1KB = 16 rows of [32] bf16 per call.
  // lane l -> row +(l>>2), 16B chunk (l&3); LDS dest is wave-uniform base (linear).
  const int sr = lane >> 2;
  const int scol = (lane & 3) * 8;
  const int gA0 = min(m0 + wave * 32 + sr, M - 1);
  const int gA1 = min(m0 + wave * 32 + 16 + sr, M - 1);
  int gB0, gB1 = 0;
  if constexpr (TN == 128) {
    gB0 = min(n0 + wave * 32 + sr, NC - 1);
    gB1 = min(n0 + wave * 32 + 16 + sr, NC - 1);
  } else {
    gB0 = min(n0 + wave * 16 + sr, NC - 1);
  }

  auto stage = [&](int buf, int kt) {
    gld16(A + (size_t)gA0 * K + kt + scol, &As[buf][(wave * 32) * 32]);
    gld16(A + (size_t)gA1 * K + kt + scol, &As[buf][(wave * 32 + 16) * 32]);
    if constexpr (TN == 128) {
      gld16(Bt + (size_t)gB0 * K + kt + scol, &Bs[buf][(wave * 32) * 32]);
      gld16(Bt + (size_t)gB1 * K + kt + scol, &Bs[buf][(wave * 32 + 16) * 32]);
    } else {
      gld16(Bt + (size_t)gB0 * K + kt + scol, &Bs[buf][(wave * 16) * 32]);
    }
  };

  f32x4 acc[MI][4] = {};

  auto compute = [&](int buf) {
    bf16x8 af[MI], bfr[4];
#pragma unroll
    for (int i = 0; i < MI; i++)
      af[i] = *(const bf16x8*)(&As[buf][(wr * WROWS + i * 16 + ln15) * 32 + q * 8]);
#pragma unroll
    for (int i = 0; i < 4; i++)
      bfr[i] = *(const bf16x8*)(&Bs[buf][(wc * 64 + i * 16 + ln15) * 32 + q * 8]);
#pragma unroll
    for (int mi = 0; mi < MI; mi++)
#pragma unroll
      for (int ni = 0; ni < 4; ni++)
        acc[mi][ni] = __builtin_amdgcn_mfma_f32_16x16x32_bf16(af[mi], bfr[ni], acc[mi][ni], 0, 0, 0);
  };

  const int NT = K >> 5;

  stage(0, 0);
  stage(1, 32);
  for (int t = 0; t < NT; ++t) {
    if (t + 2 < NT) {
      if constexpr (TN == 128) asm volatile("s_waitcnt vmcnt(4)" ::: "memory");
      else                     asm volatile("s_waitcnt vmcnt(3)" ::: "memory");
    } else {
      asm volatile("s_waitcnt vmcnt(0)" ::: "memory");
    }
    __builtin_amdgcn_sched_barrier(0);
    __builtin_amdgcn_s_barrier();  // publish tile t
    if (t + 2 < NT) stage((t + 2) % 3, (t + 2) << 5);  // issue early, lands in ~2 iters
    compute(t % 3);
    // all my ds_reads of tile t complete before I signal the next barrier
    asm volatile("s_waitcnt lgkmcnt(0)" ::: "memory");
    __builtin_amdgcn_sched_barrier(0);
  }

  // epilogue 0 (EW): acc += eW[eidx[row]][col]   (fold of the x+e edge-emb)
  if constexpr (EW) {
#pragma unroll
    for (int mi = 0; mi < MI; mi++)
#pragma unroll
      for (int r = 0; r < 4; r++) {
        int row = m0 + wr * WROWS + mi * 16 + q * 4 + r;
        int e = eidx[min(row, M - 1)];
        const float* ew = eW + e * HID + n0 + wc * 64 + ln15;
#pragma unroll
        for (int ni = 0; ni < 4; ni++) acc[mi][ni][r] += ew[ni * 16];
      }
  }

  // epilogue 1: C store. C/D layout col=lane&15, row=(lane>>4)*4+reg
#pragma unroll
  for (int mi = 0; mi < MI; mi++)
#pragma unroll
    for (int ni = 0; ni < 4; ni++)
#pragma unroll
      for (int r = 0; r < 4; r++) {
        int row = m0 + wr * WROWS + mi * 16 + q * 4 + r;
        int col = n0 + wc * 64 + ni * 16 + ln15;
        if (row < M && col < NC) C[(size_t)row * NC + col] = (OutT)acc[mi][ni][r];
      }

  // epilogue 2: attention logits. Each wave's 64-col slice == one head slice;
  // each (row, hd) produced by exactly one wave grid-wide -> plain stores.
  if (n0 + wc * 64 < NC) {
    const int hd = (n0 + wc * 64) >> 6;
#pragma unroll
    for (int mi = 0; mi < MI; mi++)
#pragma unroll
      for (int r = 0; r < 4; r++) {
        float ps = 0.f, pd = 0.f;
#pragma unroll
        for (int ni = 0; ni < 4; ni++) {
          int col = n0 + wc * 64 + ni * 16 + ln15;
          float w_s = (col < NC) ? aS[col] : 0.f;
          float w_d = (col < NC) ? aD[col] : 0.f;
          ps += acc[mi][ni][r] * w_s;
          pd += acc[mi][ni][r] * w_d;
        }
#pragma unroll
        for (int off = 1; off < 16; off <<= 1) {
          ps += __shfl_xor(ps, off);
          pd += __shfl_xor(pd, off);
        }
        int row = m0 + wr * WROWS + mi * 16 + q * 4 + r;
        if (ln15 == 0 && row < M) {
          alS[row * alStride + hd] = ps;
          alD[row * alStride + hd] = pd;
        }
      }
  }
}

// ---------------- fused gather-aggregate + LN + ELU, layer 1 ----------------
// 1 wave = 1 node (64 lanes x 4 feats, bf16x4 = 8B/lane gather loads);
// LN reduction is a pure wave shuffle — no LDS, no __syncthreads.
__global__ __launch_bounds__(256) void k_agg_ln1(const int* __restrict__ rowstart,
                                                 const int* __restrict__ deg,
                                                 const int* __restrict__ csr,
                                                 const bf16* __restrict__ h1,
                                                 const float* __restrict__ alS,
                                                 const float* __restrict__ alD,
                                                 const float* __restrict__ b1,
                                                 const float* __restrict__ g1,
                                                 const float* __restrict__ be1,
                                                 bf16* __restrict__ hln) {
  const int n = blockIdx.x * 4 + (threadIdx.x >> 6);  // 50000 % 4 == 0
  const int lane = threadIdx.x & 63;
  const int f0 = lane * 4;       // 4 consecutive feats, same head (4 | 64)
  const int hd = lane >> 4;
  int start = rowstart[n], cnt = deg[n];
  float ald = alD[n * 4 + hd];
  float accv0 = 0.f, accv1 = 0.f, accv2 = 0.f, accv3 = 0.f, accw = 0.f;
  for (int j = 0; j < cnt; j++) {
    int s = csr[start + j];
    float logit = alS[s * 4 + hd] + ald;
    logit = logit >= 0.f ? logit : 0.2f * logit;
    float w = __expf(logit);  // shift-free softmax: logits bounded by construction
    bf16x4 hv = *(const bf16x4*)(h1 + (size_t)s * HID + f0);
    accv0 += w * (float)hv[0];
    accv1 += w * (float)hv[1];
    accv2 += w * (float)hv[2];
    accv3 += w * (float)hv[3];
    accw += w;
  }
  float inv = (cnt > 0) ? 1.f / accw : 0.f;
  float4 bv = *(const float4*)(b1 + f0);
  float v0 = accv0 * inv + bv.x;
  float v1 = accv1 * inv + bv.y;
  float v2 = accv2 * inv + bv.z;
  float v3 = accv3 * inv + bv.w;
  float s = v0 + v1 + v2 + v3;
  float ss = v0 * v0 + v1 * v1 + v2 * v2 + v3 * v3;
#pragma unroll
  for (int off = 32; off; off >>= 1) { s += __shfl_xor(s, off); ss += __shfl_xor(ss, off); }
  float mu = s * (1.f / HID);
  float var = ss * (1.f / HID) - mu * mu;
  float rs = rsqrtf(var + 1e-5f);
  float4 gv = *(const float4*)(g1 + f0);
  float4 ev = *(const float4*)(be1 + f0);
  float y0 = (v0 - mu) * rs * gv.x + ev.x;
  float y1 = (v1 - mu) * rs * gv.y + ev.y;
  float y2 = (v2 - mu) * rs * gv.z + ev.z;
  float y3 = (v3 - mu) * rs * gv.w + ev.w;
  y0 = y0 > 0.f ? y0 : __expf(y0) - 1.f;  // ELU
  y1 = y1 > 0.f ? y1 : __expf(y1) - 1.f;
  y2 = y2 > 0.f ? y2 : __expf(y2) - 1.f;
  y3 = y3 > 0.f ? y3 : __expf(y3) - 1.f;
  bf16x4 o;
  o[0] = (bf16)y0; o[1] = (bf16)y1; o[2] = (bf16)y2; o[3] = (bf16)y3;
  *(bf16x4*)(hln + (size_t)n * HID + f0) = o;
}

// ---------------- fused gather-aggregate + LN, layer 2 ----------------
// 1 wave = 1 node (64 lanes x 1 fp32 feat); wave-shuffle LN.
__global__ __launch_bounds__(256) void k_agg_ln2(const int* __restrict__ rowstart,
                                                 const int* __restrict__ deg,
                                                 const int* __restrict__ csr,
                                                 const float* __restrict__ h2,
                                                 const float* __restrict__ alS,
                                                 const float* __restrict__ alD,
                                                 const float* __restrict__ b2,
                                                 const float* __restrict__ g2,
                                                 const float* __restrict__ be2,
                                                 float* __restrict__ out) {
  const int n = blockIdx.x * 4 + (threadIdx.x >> 6);
  const int f = threadIdx.x & 63;
  int start = rowstart[n], cnt = deg[n];
  float ald = alD[n];
  float accv = 0.f, accw = 0.f;
  for (int j = 0; j < cnt; j++) {
    int s = csr[start + j];
    float logit = alS[s] + ald;
    logit = logit >= 0.f ? logit : 0.2f * logit;
    float w = __expf(logit);
    accv += w * h2[(size_t)s * OUTD + f];
    accw += w;
  }
  float v = (cnt > 0) ? accv / accw : 0.f;
  v += b2[f];
  float s = v, ss = v * v;
#pragma unroll
  for (int off = 32; off; off >>= 1) { s += __shfl_xor(s, off); ss += __shfl_xor(ss, off); }
  float mu = s * (1.f / OUTD);
  float var = ss * (1.f / OUTD) - mu * mu;
  out[(size_t)n * OUTD + f] = (v - mu) * rsqrtf(var + 1e-5f) * g2[f] + be2[f];
}

extern "C" void kernel_launch(void* const* d_in, const int* in_sizes, int n_in,
                              void* d_out, int out_size, void* d_ws, size_t ws_size,
                              hipStream_t stream) {
  const float* x    = (const float*)d_in[0];
  const int*   ei   = (const int*)d_in[1];
  const int*   et   = (const int*)d_in[2];
  const float* eemb = (const float*)d_in[3];
  const float* W1   = (const float*)d_in[4];
  const float* as1  = (const float*)d_in[5];
  const float* ad1  = (const float*)d_in[6];
  const float* b1   = (const float*)d_in[7];
  const float* g1   = (const float*)d_in[8];
  const float* be1  = (const float*)d_in[9];
  const float* W2   = (const float*)d_in[10];
  const float* as2  = (const float*)d_in[11];
  const float* ad2  = (const float*)d_in[12];
  const float* b2   = (const float*)d_in[13];
  const float* g2   = (const float*)d_in[14];
  const float* be2  = (const float*)d_in[15];
  float* out = (float*)d_out;

  char* base = (char*)d_ws;
  size_t off = 0;
  auto alloc = [&](size_t bytes) -> void* {
    void* p = base + off;
    off = (off + bytes + 255) & ~(size_t)255;
    return p;
  };
  int*   le    = (int*)alloc((size_t)NN * 4);
  int*   deg   = (int*)alloc((size_t)NN * 4);
  int*   excl  = (int*)alloc((size_t)NN * 4);
  int*   bsum  = (int*)alloc(256 * 4);
  int*   bbase = (int*)alloc(256 * 4);
  int*   rowst = (int*)alloc((size_t)NN * 4);
  int*   cur   = (int*)alloc((size_t)NN * 4);
  int*   eidx  = (int*)alloc((size_t)NN * 4);
  int*   csr   = (int*)alloc((size_t)NE * 4);
  bf16*  h1    = (bf16*)alloc((size_t)NN * HID * 2);
  float* alS1  = (float*)alloc((size_t)NN * 4 * 4);
  float* alD1  = (float*)alloc((size_t)NN * 4 * 4);
  bf16*  W1t   = (bf16*)alloc((size_t)HID * IND * 2);
  bf16*  W2t   = (bf16*)alloc((size_t)OUTD * HID * 2);
  float* eW    = (float*)alloc((size_t)7 * HID * 4);
  // region R: A1 (live front..gemm1) aliased by {hln, h2, alS2, alD2} (live after gemm1)
  char*  R     = (char*)alloc((size_t)NN * IND * 2);
  bf16*  A1    = (bf16*)R;
  bf16*  hln   = (bf16*)R;
  float* h2    = (float*)(R + (size_t)NN * HID * 2);
  float* alS2  = (float*)(R + (size_t)NN * HID * 2 + (size_t)NN * OUTD * 4);
  float* alD2  = (float*)(R + (size_t)NN * HID * 2 + (size_t)NN * OUTD * 4 + (size_t)NN * 4);

  hipMemsetAsync(le, 0xFF, (size_t)NN * 4, stream);  // -1
  hipMemsetAsync(deg, 0, (size_t)NN * 4, stream);

  // one front launch: grid-stride cast (first) + edge prep + weight transposes + eW
  k_front<<<NCB + NEB + NWB, 256, 0, stream>>>(ei, le, deg, x, A1, W1, W2, eemb, W1t, W2t, eW);
  k_scan_block<<<NB, 256, 0, stream>>>(deg, excl, bsum);
  k_scan_partials<<<1, 256, 0, stream>>>(bsum, bbase);
  k_add_base<<<NB, 256, 0, stream>>>(excl, bbase, rowst, cur, le, et, eidx);
  k_scatter_csr<<<NEB, 256, 0, stream>>>(ei, cur, csr);

  // layer 1: all-gld16 pipelined bf16 GEMM, epilogue adds eW
  k_gemm_bt<bf16, 128, true><<<dim3(2, (NN + 127) / 128), 256, 0, stream>>>(
      A1, W1t, h1, NN, IND, HID, as1, ad1, alS1, alD1, 4, eidx, eW);
  k_agg_ln1<<<NN / 4, 256, 0, stream>>>(rowst, deg, csr, h1, alS1, alD1, b1, g1, be1, hln);

  // layer 2: narrow GEMM (TN=64), same pipeline
  k_gemm_bt<float, 64, false><<<dim3(1, (NN + 127) / 128), 256, 0, stream>>>(
      hln, W2t, h2, NN, HID, OUTD, as2, ad2, alS2, alD2, 1, nullptr, nullptr);
  k_agg_ln2<<<NN / 4, 256, 0, stream>>>(rowst, deg, csr, h2, alS2, alD2, b2, g2, be2, out);
}

// Round 8
// 437.403 us; speedup vs baseline: 1.2879x; 1.0224x over previous
//
#include <hip/hip_runtime.h>
#include <cstdint>
#include <cstddef>

#define NN 50000
#define NE 200000
#define IND 768
#define HID 256
#define OUTD 64
#define NB 196    // ceil(NN/256)
#define NEB 782   // ceil(NE/256) edge-prep blocks
#define NWB 1024  // weights blocks (4 x 256 linearized)
#define NCB 2048  // grid-stride cast blocks (persistent waves, ~9 iters/thread)

typedef __bf16 bf16;
typedef __bf16 bf16x8 __attribute__((ext_vector_type(8)));
typedef __bf16 bf16x4 __attribute__((ext_vector_type(4)));
typedef float f32x4 __attribute__((ext_vector_type(4)));

// ---------------- front: weights (+eW) FIRST, then cast (grid-stride), then edge-prep ----
// Round-7 postmortem: k_front's 103 us was the eW TAIL — 7 blocks at the END of the
// grid, each a 768-iteration serial FMA chain (~300cy L2 latency exposed per iter),
// running on an empty machine (Occupancy 55%, r6==r7 invariant under cast changes).
// Fix: (a) 4 independent accumulators + unroll -> chain 768 -> 192 deps, loads
// pipeline; (b) weights/eW blocks placed FIRST so any residual latency overlaps
// the 2048-block cast instead of trailing it.
__global__ __launch_bounds__(256) void k_front(const int* __restrict__ ei,
                                               int* __restrict__ le, int* __restrict__ deg,
                                               const float* __restrict__ x,
                                               bf16* __restrict__ A1,
                                               const float* __restrict__ W1,
                                               const float* __restrict__ W2,
                                               const float* __restrict__ eemb,
                                               bf16* __restrict__ W1t,
                                               bf16* __restrict__ W2t,
                                               float* __restrict__ eW) {
  const int bid = blockIdx.x, tid = threadIdx.x;
  if (bid < NWB) {
    int bx = bid >> 8, by = bid & 255;
    if (bx < 3) {
      int k = bx * 256 + tid;
      W1t[by * IND + k] = (bf16)W1[(size_t)k * HID + by];
    } else if (by < OUTD) {
      W2t[by * HID + tid] = (bf16)W2[(size_t)tid * OUTD + by];
    } else if (by < OUTD + 7) {
      int r = by - OUTD;
      float s0 = 0.f, s1 = 0.f, s2 = 0.f, s3 = 0.f;
      if (r < 6) {
        const float* er = eemb + (size_t)r * IND;
#pragma unroll 4
        for (int k = 0; k < IND; k += 4) {
          s0 += er[k]     * W1[(size_t)k * HID + tid];
          s1 += er[k + 1] * W1[(size_t)(k + 1) * HID + tid];
          s2 += er[k + 2] * W1[(size_t)(k + 2) * HID + tid];
          s3 += er[k + 3] * W1[(size_t)(k + 3) * HID + tid];
        }
      }
      eW[r * HID + tid] = (s0 + s1) + (s2 + s3);  // row 6 = zeros ("no edge")
    }
  } else if (bid < NWB + NCB) {
    const size_t total = (size_t)NN * IND / 8;  // 8 elems per thread-iteration
    const int cb = bid - NWB;
    for (size_t idx = (size_t)cb * 256 + tid; idx < total; idx += (size_t)NCB * 256) {
      const float* px = x + idx * 8;
      float4 v0 = *(const float4*)px, v1 = *(const float4*)(px + 4);
      bf16x8 o;
      o[0] = (bf16)v0.x; o[1] = (bf16)v0.y; o[2] = (bf16)v0.z; o[3] = (bf16)v0.w;
      o[4] = (bf16)v1.x; o[5] = (bf16)v1.y; o[6] = (bf16)v1.z; o[7] = (bf16)v1.w;
      *(bf16x8*)(A1 + idx * 8) = o;
    }
  } else {
    int e = (bid - NWB - NCB) * 256 + tid;
    if (e < NE) {
      atomicMax(&le[ei[e]], e);        // src: last edge index wins
      atomicAdd(&deg[ei[NE + e]], 1);  // dst degree
    }
  }
}

// ---------------- CSR build: scan + scatter ----------------
__global__ __launch_bounds__(256) void k_scan_block(const int* __restrict__ deg,
                                                    int* __restrict__ excl, int* __restrict__ bsum) {
  __shared__ int sm[256];
  int tid = threadIdx.x;
  int i = blockIdx.x * 256 + tid;
  int v = (i < NN) ? deg[i] : 0;
  sm[tid] = v;
  __syncthreads();
#pragma unroll
  for (int off = 1; off < 256; off <<= 1) {
    int t = (tid >= off) ? sm[tid - off] : 0;
    __syncthreads();
    sm[tid] += t;
    __syncthreads();
  }
  if (i < NN) excl[i] = sm[tid] - v;
  if (tid == 255) bsum[blockIdx.x] = sm[255];
}

__global__ __launch_bounds__(256) void k_scan_partials(const int* __restrict__ bsum,
                                                       int* __restrict__ bbase) {
  __shared__ int sm[256];
  int tid = threadIdx.x;
  int v = (tid < NB) ? bsum[tid] : 0;
  sm[tid] = v;
  __syncthreads();
#pragma unroll
  for (int off = 1; off < 256; off <<= 1) {
    int t = (tid >= off) ? sm[tid - off] : 0;
    __syncthreads();
    sm[tid] += t;
    __syncthreads();
  }
  bbase[tid] = sm[tid] - v;
}

// also derives eidx[i] = edge-type row for node i (6 = none) for the GEMM1 epilogue
__global__ __launch_bounds__(256) void k_add_base(const int* __restrict__ excl,
                                                  const int* __restrict__ bbase,
                                                  int* __restrict__ rowstart, int* __restrict__ cur,
                                                  const int* __restrict__ le,
                                                  const int* __restrict__ et,
                                                  int* __restrict__ eidx) {
  int i = blockIdx.x * 256 + threadIdx.x;
  if (i < NN) {
    int rs = excl[i] + bbase[i >> 8];
    rowstart[i] = rs;
    cur[i] = rs;
    int l = le[i];
    eidx[i] = (l >= 0) ? et[l] : 6;
  }
}

__global__ __launch_bounds__(256) void k_scatter_csr(const int* __restrict__ ei,
                                                     int* __restrict__ cur, int* __restrict__ csr) {
  int e = blockIdx.x * 256 + threadIdx.x;
  if (e < NE) {
    int d = ei[NE + e];
    int pos = atomicAdd(&cur[d], 1);
    csr[pos] = ei[e];  // store src node id
  }
}

__device__ __forceinline__ void gld16(const bf16* g, bf16* l) {
  __builtin_amdgcn_global_load_lds((const __attribute__((address_space(1))) void*)g,
                                   (__attribute__((address_space(3))) void*)l, 16, 0, 0);
}

// ---------------- MFMA GEMM: C[M,NC] = A[M,K] * Bt[NC,K]^T ----------------
// All-global_load_lds staging (bf16 A), 128xTN tile, BK=32, 4 waves.
// TN=128: 2x2 waves (4x4 frags); TN=64: 4x1 (2x4 frags).
// TRIPLE-buffer, distance-2, ONE barrier per K-step:
//   [vmcnt(counted)] [barrier: publish tile t] [stage t+2] [compute t]
//   [lgkmcnt(0)+sched_barrier: reads done before next barrier]
// Stage target (t+2)%3 was last read at t-1; the lgkmcnt(0) before each
// barrier guarantees those reads completed -> WAR-safe without a 2nd barrier.
// Steady vmcnt = one stage's calls (4 for TN=128, 3 for TN=64); 0 only at tail.
// EW=true: epilogue adds eW[eidx[row]] (linearity: (x+e)W = xW + eW).
// Epilogue also emits attention logits alS/alD (per-row dot with aS/aD).
template <typename OutT, int TN, bool EW>
__global__ __launch_bounds__(256) void k_gemm_bt(const bf16* __restrict__ A,
                                                 const bf16* __restrict__ Bt,
                                                 OutT* __restrict__ C,
                                                 int M, int K, int NC,
                                                 const float* __restrict__ aS,
                                                 const float* __restrict__ aD,
                                                 float* __restrict__ alS,
                                                 float* __restrict__ alD,
                                                 int alStride,
                                                 const int* __restrict__ eidx,
                                                 const float* __restrict__ eW) {
  constexpr int MI = (TN == 128) ? 4 : 2;
  constexpr int WROWS = MI * 16;
  __shared__ bf16 As[3][128 * 32];
  __shared__ bf16 Bs[3][TN * 32];
  const int tid = threadIdx.x;
  const int lane = tid & 63;
  const int wave = tid >> 6;
  const int wr = (TN == 128) ? (wave >> 1) : wave;
  const int wc = (TN == 128) ? (wave & 1) : 0;
  const int ln15 = lane & 15, q = lane >> 4;
  const int n0 = blockIdx.x * TN;  // n fastest-varying: adjacent blocks share A-tile
  const int m0 = blockIdx.y * 128;

  // gld16 staging geometry: 64 lanes x 16B = 1KB = 16 rows of [32] bf16 per call.
  // lane l -> row +(l>>2), 16B chunk (l&3); LDS dest is wave-uniform base (linear).
  const int sr = lane >> 2;
  const int scol = (lane & 3) * 8;
  const int gA0 = min(m0 + wave * 32 + sr, M - 1);
  const int gA1 = min(m0 + wave * 32 + 16 + sr, M - 1);
  int gB0, gB1 = 0;
  if constexpr (TN == 128) {
    gB0 = min(n0 + wave * 32 + sr, NC - 1);
    gB1 = min(n0 + wave * 32 + 16 + sr, NC - 1);
  } else {
    gB0 = min(n0 + wave * 16 + sr, NC - 1);
  }

  auto stage = [&](int buf, int kt) {
    gld16(A + (size_t)gA0 * K + kt + scol, &As[buf][(wave * 32) * 32]);
    gld16(A + (size_t)gA1 * K + kt + scol, &As[buf][(wave * 32 + 16) * 32]);
    if constexpr (TN == 128) {
      gld16(Bt + (size_t)gB0 * K + kt + scol, &Bs[buf][(wave * 32) * 32]);
      gld16(Bt + (size_t)gB1 * K + kt + scol, &Bs[buf][(wave * 32 + 16) * 32]);
    } else {
      gld16(Bt + (size_t)gB0 * K + kt + scol, &Bs[buf][(wave * 16) * 32]);
    }
  };

  f32x4 acc[MI][4] = {};

  auto compute = [&](int buf) {
    bf16x8 af[MI], bfr[4];
#pragma unroll
    for (int i = 0; i < MI; i++)
      af[i] = *(const bf16x8*)(&As[buf][(wr * WROWS + i * 16 + ln15) * 32 + q * 8]);
#pragma unroll
    for (int i = 0; i < 4; i++)
      bfr[i] = *(const bf16x8*)(&Bs[buf][(wc * 64 + i * 16 + ln15) * 32 + q * 8]);
#pragma unroll
    for (int mi = 0; mi < MI; mi++)
#pragma unroll
      for (int ni = 0; ni < 4; ni++)
        acc[mi][ni] = __builtin_amdgcn_mfma_f32_16x16x32_bf16(af[mi], bfr[ni], acc[mi][ni], 0, 0, 0);
  };

  const int NT = K >> 5;

  stage(0, 0);
  stage(1, 32);
  for (int t = 0; t < NT; ++t) {
    if (t + 2 < NT) {
      if constexpr (TN == 128) asm volatile("s_waitcnt vmcnt(4)" ::: "memory");
      else                     asm volatile("s_waitcnt vmcnt(3)" ::: "memory");
    } else {
      asm volatile("s_waitcnt vmcnt(0)" ::: "memory");
    }
    __builtin_amdgcn_sched_barrier(0);
    __builtin_amdgcn_s_barrier();  // publish tile t
    if (t + 2 < NT) stage((t + 2) % 3, (t + 2) << 5);  // issue early, lands in ~2 iters
    compute(t % 3);
    // all my ds_reads of tile t complete before I signal the next barrier
    asm volatile("s_waitcnt lgkmcnt(0)" ::: "memory");
    __builtin_amdgcn_sched_barrier(0);
  }

  // epilogue 0 (EW): acc += eW[eidx[row]][col]   (fold of the x+e edge-emb)
  if constexpr (EW) {
#pragma unroll
    for (int mi = 0; mi < MI; mi++)
#pragma unroll
      for (int r = 0; r < 4; r++) {
        int row = m0 + wr * WROWS + mi * 16 + q * 4 + r;
        int e = eidx[min(row, M - 1)];
        const float* ew = eW + e * HID + n0 + wc * 64 + ln15;
#pragma unroll
        for (int ni = 0; ni < 4; ni++) acc[mi][ni][r] += ew[ni * 16];
      }
  }

  // epilogue 1: C store. C/D layout col=lane&15, row=(lane>>4)*4+reg
#pragma unroll
  for (int mi = 0; mi < MI; mi++)
#pragma unroll
    for (int ni = 0; ni < 4; ni++)
#pragma unroll
      for (int r = 0; r < 4; r++) {
        int row = m0 + wr * WROWS + mi * 16 + q * 4 + r;
        int col = n0 + wc * 64 + ni * 16 + ln15;
        if (row < M && col < NC) C[(size_t)row * NC + col] = (OutT)acc[mi][ni][r];
      }

  // epilogue 2: attention logits. Each wave's 64-col slice == one head slice;
  // each (row, hd) produced by exactly one wave grid-wide -> plain stores.
  if (n0 + wc * 64 < NC) {
    const int hd = (n0 + wc * 64) >> 6;
#pragma unroll
    for (int mi = 0; mi < MI; mi++)
#pragma unroll
      for (int r = 0; r < 4; r++) {
        float ps = 0.f, pd = 0.f;
#pragma unroll
        for (int ni = 0; ni < 4; ni++) {
          int col = n0 + wc * 64 + ni * 16 + ln15;
          float w_s = (col < NC) ? aS[col] : 0.f;
          float w_d = (col < NC) ? aD[col] : 0.f;
          ps += acc[mi][ni][r] * w_s;
          pd += acc[mi][ni][r] * w_d;
        }
#pragma unroll
        for (int off = 1; off < 16; off <<= 1) {
          ps += __shfl_xor(ps, off);
          pd += __shfl_xor(pd, off);
        }
        int row = m0 + wr * WROWS + mi * 16 + q * 4 + r;
        if (ln15 == 0 && row < M) {
          alS[row * alStride + hd] = ps;
          alD[row * alStride + hd] = pd;
        }
      }
  }
}

// ---------------- fused gather-aggregate + LN + ELU, layer 1 ----------------
// 1 wave = 1 node (64 lanes x 4 feats, bf16x4 = 8B/lane gather loads);
// LN reduction is a pure wave shuffle — no LDS, no __syncthreads.
__global__ __launch_bounds__(256) void k_agg_ln1(const int* __restrict__ rowstart,
                                                 const int* __restrict__ deg,
                                                 const int* __restrict__ csr,
                                                 const bf16* __restrict__ h1,
                                                 const float* __restrict__ alS,
                                                 const float* __restrict__ alD,
                                                 const float* __restrict__ b1,
                                                 const float* __restrict__ g1,
                                                 const float* __restrict__ be1,
                                                 bf16* __restrict__ hln) {
  const int n = blockIdx.x * 4 + (threadIdx.x >> 6);  // 50000 % 4 == 0
  const int lane = threadIdx.x & 63;
  const int f0 = lane * 4;       // 4 consecutive feats, same head (4 | 64)
  const int hd = lane >> 4;
  int start = rowstart[n], cnt = deg[n];
  float ald = alD[n * 4 + hd];
  float accv0 = 0.f, accv1 = 0.f, accv2 = 0.f, accv3 = 0.f, accw = 0.f;
  for (int j = 0; j < cnt; j++) {
    int s = csr[start + j];
    float logit = alS[s * 4 + hd] + ald;
    logit = logit >= 0.f ? logit : 0.2f * logit;
    float w = __expf(logit);  // shift-free softmax: logits bounded by construction
    bf16x4 hv = *(const bf16x4*)(h1 + (size_t)s * HID + f0);
    accv0 += w * (float)hv[0];
    accv1 += w * (float)hv[1];
    accv2 += w * (float)hv[2];
    accv3 += w * (float)hv[3];
    accw += w;
  }
  float inv = (cnt > 0) ? 1.f / accw : 0.f;
  float4 bv = *(const float4*)(b1 + f0);
  float v0 = accv0 * inv + bv.x;
  float v1 = accv1 * inv + bv.y;
  float v2 = accv2 * inv + bv.z;
  float v3 = accv3 * inv + bv.w;
  float s = v0 + v1 + v2 + v3;
  float ss = v0 * v0 + v1 * v1 + v2 * v2 + v3 * v3;
#pragma unroll
  for (int off = 32; off; off >>= 1) { s += __shfl_xor(s, off); ss += __shfl_xor(ss, off); }
  float mu = s * (1.f / HID);
  float var = ss * (1.f / HID) - mu * mu;
  float rs = rsqrtf(var + 1e-5f);
  float4 gv = *(const float4*)(g1 + f0);
  float4 ev = *(const float4*)(be1 + f0);
  float y0 = (v0 - mu) * rs * gv.x + ev.x;
  float y1 = (v1 - mu) * rs * gv.y + ev.y;
  float y2 = (v2 - mu) * rs * gv.z + ev.z;
  float y3 = (v3 - mu) * rs * gv.w + ev.w;
  y0 = y0 > 0.f ? y0 : __expf(y0) - 1.f;  // ELU
  y1 = y1 > 0.f ? y1 : __expf(y1) - 1.f;
  y2 = y2 > 0.f ? y2 : __expf(y2) - 1.f;
  y3 = y3 > 0.f ? y3 : __expf(y3) - 1.f;
  bf16x4 o;
  o[0] = (bf16)y0; o[1] = (bf16)y1; o[2] = (bf16)y2; o[3] = (bf16)y3;
  *(bf16x4*)(hln + (size_t)n * HID + f0) = o;
}

// ---------------- fused gather-aggregate + LN, layer 2 ----------------
// 1 wave = 1 node (64 lanes x 1 fp32 feat); wave-shuffle LN.
__global__ __launch_bounds__(256) void k_agg_ln2(const int* __restrict__ rowstart,
                                                 const int* __restrict__ deg,
                                                 const int* __restrict__ csr,
                                                 const float* __restrict__ h2,
                                                 const float* __restrict__ alS,
                                                 const float* __restrict__ alD,
                                                 const float* __restrict__ b2,
                                                 const float* __restrict__ g2,
                                                 const float* __restrict__ be2,
                                                 float* __restrict__ out) {
  const int n = blockIdx.x * 4 + (threadIdx.x >> 6);
  const int f = threadIdx.x & 63;
  int start = rowstart[n], cnt = deg[n];
  float ald = alD[n];
  float accv = 0.f, accw = 0.f;
  for (int j = 0; j < cnt; j++) {
    int s = csr[start + j];
    float logit = alS[s] + ald;
    logit = logit >= 0.f ? logit : 0.2f * logit;
    float w = __expf(logit);
    accv += w * h2[(size_t)s * OUTD + f];
    accw += w;
  }
  float v = (cnt > 0) ? accv / accw : 0.f;
  v += b2[f];
  float s = v, ss = v * v;
#pragma unroll
  for (int off = 32; off; off >>= 1) { s += __shfl_xor(s, off); ss += __shfl_xor(ss, off); }
  float mu = s * (1.f / OUTD);
  float var = ss * (1.f / OUTD) - mu * mu;
  out[(size_t)n * OUTD + f] = (v - mu) * rsqrtf(var + 1e-5f) * g2[f] + be2[f];
}

extern "C" void kernel_launch(void* const* d_in, const int* in_sizes, int n_in,
                              void* d_out, int out_size, void* d_ws, size_t ws_size,
                              hipStream_t stream) {
  const float* x    = (const float*)d_in[0];
  const int*   ei   = (const int*)d_in[1];
  const int*   et   = (const int*)d_in[2];
  const float* eemb = (const float*)d_in[3];
  const float* W1   = (const float*)d_in[4];
  const float* as1  = (const float*)d_in[5];
  const float* ad1  = (const float*)d_in[6];
  const float* b1   = (const float*)d_in[7];
  const float* g1   = (const float*)d_in[8];
  const float* be1  = (const float*)d_in[9];
  const float* W2   = (const float*)d_in[10];
  const float* as2  = (const float*)d_in[11];
  const float* ad2  = (const float*)d_in[12];
  const float* b2   = (const float*)d_in[13];
  const float* g2   = (const float*)d_in[14];
  const float* be2  = (const float*)d_in[15];
  float* out = (float*)d_out;

  char* base = (char*)d_ws;
  size_t off = 0;
  auto alloc = [&](size_t bytes) -> void* {
    void* p = base + off;
    off = (off + bytes + 255) & ~(size_t)255;
    return p;
  };
  int*   le    = (int*)alloc((size_t)NN * 4);
  int*   deg   = (int*)alloc((size_t)NN * 4);
  int*   excl  = (int*)alloc((size_t)NN * 4);
  int*   bsum  = (int*)alloc(256 * 4);
  int*   bbase = (int*)alloc(256 * 4);
  int*   rowst = (int*)alloc((size_t)NN * 4);
  int*   cur   = (int*)alloc((size_t)NN * 4);
  int*   eidx  = (int*)alloc((size_t)NN * 4);
  int*   csr   = (int*)alloc((size_t)NE * 4);
  bf16*  h1    = (bf16*)alloc((size_t)NN * HID * 2);
  float* alS1  = (float*)alloc((size_t)NN * 4 * 4);
  float* alD1  = (float*)alloc((size_t)NN * 4 * 4);
  bf16*  W1t   = (bf16*)alloc((size_t)HID * IND * 2);
  bf16*  W2t   = (bf16*)alloc((size_t)OUTD * HID * 2);
  float* eW    = (float*)alloc((size_t)7 * HID * 4);
  // region R: A1 (live front..gemm1) aliased by {hln, h2, alS2, alD2} (live after gemm1)
  char*  R     = (char*)alloc((size_t)NN * IND * 2);
  bf16*  A1    = (bf16*)R;
  bf16*  hln   = (bf16*)R;
  float* h2    = (float*)(R + (size_t)NN * HID * 2);
  float* alS2  = (float*)(R + (size_t)NN * HID * 2 + (size_t)NN * OUTD * 4);
  float* alD2  = (float*)(R + (size_t)NN * HID * 2 + (size_t)NN * OUTD * 4 + (size_t)NN * 4);

  hipMemsetAsync(le, 0xFF, (size_t)NN * 4, stream);  // -1
  hipMemsetAsync(deg, 0, (size_t)NN * 4, stream);

  // one front launch: weights+eW (first), grid-stride cast, edge prep
  k_front<<<NWB + NCB + NEB, 256, 0, stream>>>(ei, le, deg, x, A1, W1, W2, eemb, W1t, W2t, eW);
  k_scan_block<<<NB, 256, 0, stream>>>(deg, excl, bsum);
  k_scan_partials<<<1, 256, 0, stream>>>(bsum, bbase);
  k_add_base<<<NB, 256, 0, stream>>>(excl, bbase, rowst, cur, le, et, eidx);
  k_scatter_csr<<<NEB, 256, 0, stream>>>(ei, cur, csr);

  // layer 1: all-gld16 pipelined bf16 GEMM, epilogue adds eW
  k_gemm_bt<bf16, 128, true><<<dim3(2, (NN + 127) / 128), 256, 0, stream>>>(
      A1, W1t, h1, NN, IND, HID, as1, ad1, alS1, alD1, 4, eidx, eW);
  k_agg_ln1<<<NN / 4, 256, 0, stream>>>(rowst, deg, csr, h1, alS1, alD1, b1, g1, be1, hln);

  // layer 2: narrow GEMM (TN=64), same pipeline
  k_gemm_bt<float, 64, false><<<dim3(1, (NN + 127) / 128), 256, 0, stream>>>(
      hln, W2t, h2, NN, HID, OUTD, as2, ad2, alS2, alD2, 1, nullptr, nullptr);
  k_agg_ln2<<<NN / 4, 256, 0, stream>>>(rowst, deg, csr, h2, alS2, alD2, b2, g2, be2, out);
}